// Round 8
// baseline (204.334 us; speedup 1.0000x reference)
//
#include <hip/hip_runtime.h>
#include <hip/hip_bf16.h>
#include <stdint.h>

#define N_TOK 4096
#define CDIM 768
#define NH 12
#define HD 64
#define SX (N_TOK * CDIM)
#define SW (CDIM * CDIM)

typedef __attribute__((ext_vector_type(8))) short bf16x8;
typedef __attribute__((ext_vector_type(4))) float f32x4;
typedef __attribute__((ext_vector_type(16))) float f32x16;
typedef unsigned short ushort_t;
typedef unsigned int uint_t;

typedef const __attribute__((address_space(1))) void* as1_cvp;
typedef __attribute__((address_space(3))) void* as3_vp;
#define GLD16(g, s) __builtin_amdgcn_global_load_lds((as1_cvp)(g), (as3_vp)(s), 16, 0, 0)

__device__ inline ushort_t f2bf(float f) {
    union { float f; uint_t u; } c; c.f = f;
    uint_t u = (c.u + 0x7FFFu + ((c.u >> 16) & 1u)) >> 16;
    return (ushort_t)u;
}
__device__ inline uint_t pack_bf2(float a, float b) {
    union { __hip_bfloat162 v; uint_t u; } c;
    c.v = __float22bfloat162_rn(make_float2(a, b));
    return c.u;
}

// fp32 -> bf16 one-shot conversion of x, Wq|Wk|Wv (concat), Wo; bq|bk|bv concat fp32.
__global__ __launch_bounds__(256) void convert_all(
    const float* __restrict__ x,
    const float* __restrict__ Wq, const float* __restrict__ Wk,
    const float* __restrict__ Wv, const float* __restrict__ Wo,
    const float* __restrict__ bq, const float* __restrict__ bk, const float* __restrict__ bv,
    ushort_t* __restrict__ xb, ushort_t* __restrict__ Wf,
    ushort_t* __restrict__ Wob, float* __restrict__ biasf)
{
    long i = ((long)blockIdx.x * 256 + threadIdx.x) * 4;
    const float* src; ushort_t* dst; long off;
    if (i < SX)               { src = x;  dst = xb;          off = i; }
    else if (i < SX + SW)     { src = Wq; dst = Wf;          off = i - SX; }
    else if (i < SX + 2*SW)   { src = Wk; dst = Wf + SW;     off = i - SX - SW; }
    else if (i < SX + 3*SW)   { src = Wv; dst = Wf + 2*SW;   off = i - SX - 2*SW; }
    else if (i < SX + 4*SW)   { src = Wo; dst = Wob;         off = i - SX - 3*SW; }
    else if (i < SX + 4*SW + 3*CDIM) {
        long b = i - (SX + 4*SW);
        const float* bs = (b < CDIM) ? bq + b : (b < 2*CDIM) ? bk + (b - CDIM) : bv + (b - 2*CDIM);
        *(float4*)(biasf + b) = *(const float4*)bs;
        return;
    } else return;
    float4 v4 = *(const float4*)(src + off);
    uint2 st = { pack_bf2(v4.x, v4.y), pack_bf2(v4.z, v4.w) };
    *(uint2*)(dst + off) = st;
}

// Fused QKV GEMM v2: 128x96 tiles -> grid 32x24 = 768 blocks = 3/CU EXACT
// (was 128x64, 1152 blocks = 4.5/CU imbalanced). 768/96=8 so each tile lies
// wholly in Q (y<8), K (y<16) or V. BK=64, GLD16 staging, XOR-swizzled LDS.
// out[i][j] = sum_c xb[i][c]*Wf[j][c] + biasf[j]; q PRE-SCALED by C1; v stored
// transposed vT[j][i].
__global__ __launch_bounds__(256) void gemm_qkv(
    const ushort_t* __restrict__ xb, const ushort_t* __restrict__ Wf,
    const float* __restrict__ biasf,
    ushort_t* __restrict__ q, ushort_t* __restrict__ k, ushort_t* __restrict__ vT)
{
    __shared__ __align__(16) ushort_t smemAB[224 * 64];   // A[128][64] | B[96][64]
    ushort_t* Asm = smemAB;
    ushort_t* Bsm = smemAB + 128 * 64;
    const int tid = threadIdx.x;
    const int w = tid >> 6, lane = tid & 63;
    const int quad = lane >> 4, l16 = lane & 15;
    const int row0 = blockIdx.x * 128;
    const int col0 = blockIdx.y * 96;
    const int rw = w * 32;
    const int srow = lane >> 3;
    const int sc = ((lane & 7) ^ srow) * 8;
    const int swz = l16 & 7;
    const float C1 = 0.18033688011112042f;   // 0.125 * log2(e)

    f32x4 acc[2][6];
#pragma unroll
    for (int a = 0; a < 2; a++)
#pragma unroll
        for (int b = 0; b < 6; b++) acc[a][b] = (f32x4){0.f, 0.f, 0.f, 0.f};

    for (int kc = 0; kc < CDIM; kc += 64) {
        __syncthreads();
#pragma unroll
        for (int c = 0; c < 4; c++) {
            int ra = w * 32 + c * 8;
            GLD16(xb + (size_t)(row0 + ra + srow) * CDIM + kc + sc, &Asm[ra * 64]);
        }
#pragma unroll
        for (int c = 0; c < 3; c++) {
            int rb_ = w * 24 + c * 8;
            GLD16(Wf + (size_t)(col0 + rb_ + srow) * CDIM + kc + sc, &Bsm[rb_ * 64]);
        }
        __syncthreads();
#pragma unroll
        for (int kk = 0; kk < 2; kk++) {
            const int po = ((kk * 4 + quad) ^ swz) * 8;
            bf16x8 af[2], bfr[6];
#pragma unroll
            for (int rb = 0; rb < 2; rb++)
                af[rb] = *(const bf16x8*)&Asm[(rw + rb * 16 + l16) * 64 + po];
#pragma unroll
            for (int cb = 0; cb < 6; cb++)
                bfr[cb] = *(const bf16x8*)&Bsm[(cb * 16 + l16) * 64 + po];
#pragma unroll
            for (int rb = 0; rb < 2; rb++)
#pragma unroll
                for (int cb = 0; cb < 6; cb++)
                    acc[rb][cb] = __builtin_amdgcn_mfma_f32_16x16x32_bf16(af[rb], bfr[cb], acc[rb][cb], 0, 0, 0);
        }
    }

    if (col0 < 2 * CDIM) {
        const bool isQ = (col0 < CDIM);
        ushort_t* dst = isQ ? q : k;
        const int jb0 = isQ ? col0 : col0 - CDIM;
        const float scale = isQ ? C1 : 1.0f;
#pragma unroll
        for (int cb = 0; cb < 6; cb++) {
            int j = jb0 + cb * 16 + l16;
            float bv_ = biasf[col0 + cb * 16 + l16];
#pragma unroll
            for (int rb = 0; rb < 2; rb++)
#pragma unroll
                for (int r = 0; r < 4; r++) {
                    int i = row0 + rw + rb * 16 + quad * 4 + r;
                    dst[(size_t)i * CDIM + j] = f2bf((acc[rb][cb][r] + bv_) * scale);
                }
        }
    } else {
        // vT: 96j x 128i transpose through smemAB (swizzled), coalesced stores
        const int jv0 = col0 - 2 * CDIM;
        ushort_t* T = smemAB;   // [96][128] = 24 KB <= 28 KB
        __syncthreads();
#pragma unroll
        for (int cb = 0; cb < 6; cb++) {
            int jl = cb * 16 + l16;
            float bv_ = biasf[col0 + jl];
#pragma unroll
            for (int rb = 0; rb < 2; rb++)
#pragma unroll
                for (int r = 0; r < 4; r++) {
                    int i = rw + rb * 16 + quad * 4 + r;
                    T[jl * 128 + (((i >> 3) ^ (jl & 7)) * 8) + (i & 7)] =
                        f2bf(acc[rb][cb][r] + bv_);
                }
        }
        __syncthreads();
#pragma unroll
        for (int p = 0; p < 6; p++) {
            int t = tid + p * 256, jl = t >> 4, i8 = t & 15;
            *(bf16x8*)(vT + (size_t)(jv0 + jl) * N_TOK + row0 + i8 * 8) =
                *(const bf16x8*)&T[jl * 128 + ((i8 ^ (jl & 7)) * 8)];
        }
    }
}

// Output projection: 64x64 tiles (768 blocks = 3/CU balanced). fp32 out.
__global__ __launch_bounds__(256) void gemm_out(
    const ushort_t* __restrict__ A, const ushort_t* __restrict__ W,
    const float* __restrict__ bias, float* __restrict__ out)
{
    __shared__ __align__(16) ushort_t Asm[64 * 64];
    __shared__ __align__(16) ushort_t Bsm[64 * 64];
    const int tid = threadIdx.x;
    const int w = tid >> 6, lane = tid & 63;
    const int quad = lane >> 4, l16 = lane & 15;
    const int row0 = blockIdx.x * 64;
    const int col0 = blockIdx.y * 64;
    const int srow = lane >> 3;
    const int sc = ((lane & 7) ^ srow) * 8;
    const int swz = l16 & 7;

    f32x4 acc[4];
#pragma unroll
    for (int b = 0; b < 4; b++) acc[b] = (f32x4){0.f, 0.f, 0.f, 0.f};

    for (int kc = 0; kc < CDIM; kc += 64) {
        __syncthreads();
#pragma unroll
        for (int c = 0; c < 2; c++) {
            int ra = w * 16 + c * 8;
            GLD16(A + (size_t)(row0 + ra + srow) * CDIM + kc + sc, &Asm[ra * 64]);
            GLD16(W + (size_t)(col0 + ra + srow) * CDIM + kc + sc, &Bsm[ra * 64]);
        }
        __syncthreads();
#pragma unroll
        for (int kk = 0; kk < 2; kk++) {
            const int po = ((kk * 4 + quad) ^ swz) * 8;
            bf16x8 af = *(const bf16x8*)&Asm[(w * 16 + l16) * 64 + po];
#pragma unroll
            for (int cb = 0; cb < 4; cb++) {
                bf16x8 bfr = *(const bf16x8*)&Bsm[(cb * 16 + l16) * 64 + po];
                acc[cb] = __builtin_amdgcn_mfma_f32_16x16x32_bf16(af, bfr, acc[cb], 0, 0, 0);
            }
        }
    }
#pragma unroll
    for (int cb = 0; cb < 4; cb++) {
        int j = col0 + cb * 16 + l16;
        float bv_ = bias[j];
#pragma unroll
        for (int r = 0; r < 4; r++) {
            int i = row0 + w * 16 + quad * 4 + r;
            out[(size_t)i * CDIM + j] = acc[cb][r] + bv_;
        }
    }
}

// Flash attention v10 (round-7 PASSING kernel, 96.6us, byte-identical): v6 base
// (32x32x16 MFMA, swapped QK^T, in-register P via cvt_pk + permlane32_swap,
// QBLK=64, 2-buffer GLD16 staging, XCD swizzle) + per-THREAD filtered bias queue
// with 2-deep register lookahead.
__global__ __launch_bounds__(256, 3) void attn_kernel(
    const ushort_t* __restrict__ Q, const ushort_t* __restrict__ K,
    const ushort_t* __restrict__ VT, const int* __restrict__ sim,
    ushort_t* __restrict__ Oout)
{
    // smem: K tiles [2][64][64] bf16 | V tiles [2][64][64] bf16 (32 KB total).
    // After the loop, aliased as Of f32[64][66] for the O combine (16.9 KB).
    __shared__ __align__(16) ushort_t smem[16384];
    __shared__ ushort_t bq_[256 * 12];   // per-thread filtered bias queue
    __shared__ float psum[128];          // [qs][jh][l32]

    const int tid = threadIdx.x;
    const int w = tid >> 6, lane = tid & 63;
    const int hi = lane >> 5, l32 = lane & 31;
    const int qs = w >> 1, jh = w & 1;
    const float LOG2E = 1.4426950408889634f;

    // bijective XCD swizzle: 768 = 8 XCDs x 96; each XCD gets 1.5 contiguous heads
    const int lin = blockIdx.x;
    const int g = (lin & 7) * 96 + (lin >> 3);
    const int qbase = (g & 63) * 64;
    const int hoff = (g >> 6) * HD;

    // ---- staging (pre-swizzled global source -> linear LDS dest) ----
    const int srow = lane >> 3;
    const int sc = ((lane & 7) ^ srow) * 8;
    const ushort_t* kg0 = K + (size_t)(w * 16 + srow) * CDIM + hoff + sc;
    const ushort_t* kg1 = kg0 + 8 * CDIM;
    const ushort_t* vg0 = VT + (size_t)(hoff + w * 16 + srow) * N_TOK + sc;
    const ushort_t* vg1 = vg0 + 8 * (size_t)N_TOK;
    ushort_t* kda = &smem[(w * 16) * 64];
    ushort_t* vda = &smem[8192 + (w * 16) * 64];

#define STAGE(KD, VD) do { \
    GLD16(kg0, (KD)); GLD16(kg1, (KD) + 512); \
    GLD16(vg0, (VD)); GLD16(vg1, (VD) + 512); \
    kg0 += 64 * CDIM; kg1 += 64 * CDIM; vg0 += 64; vg1 += 64; } while (0)

    // ---- per-thread filtered bias queue (thread-private: no barrier needed) ----
    // Lane's sacc element r (hi half) holds S^T[jloc=(r&3)+8*(r>>2)+4*hi][i=l32].
    // Entry j relevant iff bit5(j)==jh && bit2(j)==hi; code = (j>>6)<<4 | r where
    // r = (j&3) + 4*((j&31)>>3).
    ushort_t* myq = &bq_[tid * 12];
    {
        int vb_[10];
        const int* sp = sim + (size_t)(qbase + qs * 32 + l32) * 10;
#pragma unroll
        for (int e = 0; e < 10; e++) vb_[e] = sp[e];
#pragma unroll
        for (int round = 0; round < 10; round++)
#pragma unroll
            for (int i = (round & 1); i + 1 < 10; i += 2) {
                int a = vb_[i], b = vb_[i + 1];
                vb_[i] = min(a, b); vb_[i + 1] = max(a, b);
            }
        int n = 0;
#pragma unroll
        for (int e = 0; e < 10; e++) {
            int j = vb_[e];
            if ((((j >> 5) & 1) == jh) && (((j >> 2) & 1) == hi))
                myq[n++] = (ushort_t)(((j >> 6) << 4) | ((j & 3) + 4 * ((j & 31) >> 3)));
        }
        for (; n < 12; n++) myq[n] = 0xFFFFu;   // sentinel tile 4095
    }
    uint_t c0 = myq[0], c1 = myq[1];
    int qpt = 2;

    // ---- Q fragments (B-operand of S^T MFMA): rows i = qbase+qs*32+l32 ----
    bf16x8 qf[4];
    {
        const ushort_t* qp = Q + (size_t)(qbase + qs * 32 + l32) * CDIM + hoff + hi * 8;
#pragma unroll
        for (int kk = 0; kk < 4; kk++) qf[kk] = *(const bf16x8*)(qp + kk * 16);
    }

    // ---- hoisted tile-invariant LDS read pointers (buf0; buf1 = +4096) ----
    const int swz = l32 & 7;
    const ushort_t* kfp[4];
#pragma unroll
    for (int kk = 0; kk < 4; kk++)
        kfp[kk] = &smem[(jh * 32 + l32) * 64 + (((kk * 2 + hi) ^ swz) * 8)];
    const ushort_t* vfp[2][2];
#pragma unroll
    for (int db = 0; db < 2; db++)
#pragma unroll
        for (int k2 = 0; k2 < 2; k2++)
            vfp[db][k2] = &smem[8192 + db * 2048 + l32 * 64 + (((jh * 4 + k2 * 2 + hi) ^ swz) * 8)];

    STAGE(kda, vda);          // tile 0 -> buf0
    __syncthreads();          // tile0 visible

    float lsum = 0.f;
    f32x16 Oacc0 = {0.f,0.f,0.f,0.f,0.f,0.f,0.f,0.f,0.f,0.f,0.f,0.f,0.f,0.f,0.f,0.f};
    f32x16 Oacc1 = {0.f,0.f,0.f,0.f,0.f,0.f,0.f,0.f,0.f,0.f,0.f,0.f,0.f,0.f,0.f,0.f};

    // One tile: S^T MFMA (A=K from LDS, B=Q regs) -> queue-walk bias -> exp2 ->
    // cvt_pk + permlane32_swap (P A-frags in regs) -> PV MFMA (B=V from LDS).
#define TILE_BODY(OFS, J0) do { \
    f32x16 sacc = {0.f,0.f,0.f,0.f,0.f,0.f,0.f,0.f,0.f,0.f,0.f,0.f,0.f,0.f,0.f,0.f}; \
    _Pragma("unroll") \
    for (int kk = 0; kk < 4; kk++) { \
        bf16x8 kf = *(const bf16x8*)(kfp[kk] + (OFS)); \
        sacc = __builtin_amdgcn_mfma_f32_32x32x16_bf16(kf, qf[kk], sacc, 0, 0, 0); \
    } \
    while ((c0 >> 4) == (uint_t)((J0) >> 6)) { \
        int r = (int)(c0 & 15u); \
        sacc[0]  += (r == 0)  ? LOG2E : 0.f; \
        sacc[1]  += (r == 1)  ? LOG2E : 0.f; \
        sacc[2]  += (r == 2)  ? LOG2E : 0.f; \
        sacc[3]  += (r == 3)  ? LOG2E : 0.f; \
        sacc[4]  += (r == 4)  ? LOG2E : 0.f; \
        sacc[5]  += (r == 5)  ? LOG2E : 0.f; \
        sacc[6]  += (r == 6)  ? LOG2E : 0.f; \
        sacc[7]  += (r == 7)  ? LOG2E : 0.f; \
        sacc[8]  += (r == 8)  ? LOG2E : 0.f; \
        sacc[9]  += (r == 9)  ? LOG2E : 0.f; \
        sacc[10] += (r == 10) ? LOG2E : 0.f; \
        sacc[11] += (r == 11) ? LOG2E : 0.f; \
        sacc[12] += (r == 12) ? LOG2E : 0.f; \
        sacc[13] += (r == 13) ? LOG2E : 0.f; \
        sacc[14] += (r == 14) ? LOG2E : 0.f; \
        sacc[15] += (r == 15) ? LOG2E : 0.f; \
        c0 = c1; c1 = myq[qpt]; qpt++; \
    } \
    float e0  = __builtin_amdgcn_exp2f(sacc[0]); \
    float e1  = __builtin_amdgcn_exp2f(sacc[1]); \
    float e2  = __builtin_amdgcn_exp2f(sacc[2]); \
    float e3  = __builtin_amdgcn_exp2f(sacc[3]); \
    float e4  = __builtin_amdgcn_exp2f(sacc[4]); \
    float e5  = __builtin_amdgcn_exp2f(sacc[5]); \
    float e6  = __builtin_amdgcn_exp2f(sacc[6]); \
    float e7  = __builtin_amdgcn_exp2f(sacc[7]); \
    float e8  = __builtin_amdgcn_exp2f(sacc[8]); \
    float e9  = __builtin_amdgcn_exp2f(sacc[9]); \
    float e10 = __builtin_amdgcn_exp2f(sacc[10]); \
    float e11 = __builtin_amdgcn_exp2f(sacc[11]); \
    float e12 = __builtin_amdgcn_exp2f(sacc[12]); \
    float e13 = __builtin_amdgcn_exp2f(sacc[13]); \
    float e14 = __builtin_amdgcn_exp2f(sacc[14]); \
    float e15 = __builtin_amdgcn_exp2f(sacc[15]); \
    lsum += (((e0+e1)+(e2+e3)) + ((e4+e5)+(e6+e7))) \
          + (((e8+e9)+(e10+e11)) + ((e12+e13)+(e14+e15))); \
    uint_t A0 = pack_bf2(e0, e1),   C0 = pack_bf2(e2, e3); \
    uint_t B0 = pack_bf2(e4, e5),   D0 = pack_bf2(e6, e7); \
    uint_t A1 = pack_bf2(e8, e9),   C1_ = pack_bf2(e10, e11); \
    uint_t B1 = pack_bf2(e12, e13), D1 = pack_bf2(e14, e15); \
    asm("v_permlane32_swap_b32 %0, %1" : "+v"(A0), "+v"(B0)); \
    asm("v_permlane32_swap_b32 %0, %1" : "+v"(C0), "+v"(D0)); \
    asm("v_permlane32_swap_b32 %0, %1" : "+v"(A1), "+v"(B1)); \
    asm("v_permlane32_swap_b32 %0, %1" : "+v"(C1_), "+v"(D1)); \
    union { uint_t u[4]; bf16x8 v; } pa0_, pa1_; \
    pa0_.u[0] = A0; pa0_.u[1] = C0; pa0_.u[2] = B0; pa0_.u[3] = D0; \
    pa1_.u[0] = A1; pa1_.u[1] = C1_; pa1_.u[2] = B1; pa1_.u[3] = D1; \
    { \
        bf16x8 v00 = *(const bf16x8*)(vfp[0][0] + (OFS)); \
        bf16x8 v01 = *(const bf16x8*)(vfp[0][1] + (OFS)); \
        Oacc0 = __builtin_amdgcn_mfma_f32_32x32x16_bf16(pa0_.v, v00, Oacc0, 0, 0, 0); \
        Oacc0 = __builtin_amdgcn_mfma_f32_32x32x16_bf16(pa1_.v, v01, Oacc0, 0, 0, 0); \
        bf16x8 v10 = *(const bf16x8*)(vfp[1][0] + (OFS)); \
        bf16x8 v11 = *(const bf16x8*)(vfp[1][1] + (OFS)); \
        Oacc1 = __builtin_amdgcn_mfma_f32_32x32x16_bf16(pa0_.v, v10, Oacc1, 0, 0, 0); \
        Oacc1 = __builtin_amdgcn_mfma_f32_32x32x16_bf16(pa1_.v, v11, Oacc1, 0, 0, 0); \
    } \
  } while (0)

    // main loop: 64 tiles, 2-deep unrolled for compile-time buffer selection.
    for (int t = 0; t < 64; t += 2) {
        STAGE(kda + 4096, vda + 4096);          // tile t+1 -> buf1
        TILE_BODY(0, t * 64);
        __syncthreads();
        if (t + 2 < 64) STAGE(kda, vda);        // tile t+2 -> buf0
        TILE_BODY(4096, (t + 1) * 64);
        __syncthreads();
    }
#undef TILE_BODY
#undef STAGE

    // ---- epilogue: l reduce, O combine across jh halves, normalize, store ----
    float lt = lsum + __shfl_xor(lsum, 32, 64);
    if (lane < 32) psum[qs * 64 + jh * 32 + l32] = lt;

    float* Of = (float*)smem;   // [64][66]
#define OROWS(OACC, DB, OP) do { \
    _Pragma("unroll") \
    for (int r = 0; r < 16; r++) { \
        int i_ = qs * 32 + (r & 3) + 8 * (r >> 2) + 4 * hi; \
        Of[i_ * 66 + (DB) * 32 + l32] OP (OACC)[r]; \
    } } while (0)

    if (jh == 0) { OROWS(Oacc0, 0, =); OROWS(Oacc1, 1, =); }
    __syncthreads();
    if (jh == 1) { OROWS(Oacc0, 0, +=); OROWS(Oacc1, 1, +=); }
    __syncthreads();
#undef OROWS

    {
        int row = tid >> 2, cs = (tid & 3) * 16;
        int li = row & 31, qr = row >> 5;
        float inv = 1.0f / (psum[qr * 64 + li] + psum[qr * 64 + 32 + li]);
        const float* rp = Of + row * 66 + cs;
        uint_t w0 = pack_bf2(rp[0]  * inv, rp[1]  * inv);
        uint_t w1 = pack_bf2(rp[2]  * inv, rp[3]  * inv);
        uint_t w2 = pack_bf2(rp[4]  * inv, rp[5]  * inv);
        uint_t w3 = pack_bf2(rp[6]  * inv, rp[7]  * inv);
        uint_t w4 = pack_bf2(rp[8]  * inv, rp[9]  * inv);
        uint_t w5 = pack_bf2(rp[10] * inv, rp[11] * inv);
        uint_t w6 = pack_bf2(rp[12] * inv, rp[13] * inv);
        uint_t w7 = pack_bf2(rp[14] * inv, rp[15] * inv);
        union { uint_t u[4]; bf16x8 v; } oA, oB;
        oA.u[0] = w0; oA.u[1] = w1; oA.u[2] = w2; oA.u[3] = w3;
        oB.u[0] = w4; oB.u[1] = w5; oB.u[2] = w6; oB.u[3] = w7;
        ushort_t* op = Oout + (size_t)(qbase + row) * CDIM + hoff + cs;
        *(bf16x8*)op = oA.v;
        *(bf16x8*)(op + 8) = oB.v;
    }
}

extern "C" void kernel_launch(void* const* d_in, const int* in_sizes, int n_in,
                              void* d_out, int out_size, void* d_ws, size_t ws_size,
                              hipStream_t stream)
{
    const float* x   = (const float*)d_in[0];
    const int*   sim = (const int*)d_in[1];
    const float* Wq  = (const float*)d_in[2];
    const float* bq  = (const float*)d_in[3];
    const float* Wk  = (const float*)d_in[4];
    const float* bk  = (const float*)d_in[5];
    const float* Wv  = (const float*)d_in[6];
    const float* bv  = (const float*)d_in[7];
    const float* Wo  = (const float*)d_in[8];
    const float* bo  = (const float*)d_in[9];
    float* out = (float*)d_out;

    // ws layout (ushort units): xb(=ao) | q | k | vT | Wf | Wob | biasf(fp32)
    ushort_t* xb  = (ushort_t*)d_ws;
    ushort_t* q   = xb + SX;
    ushort_t* k   = q + SX;
    ushort_t* vT  = k + SX;
    ushort_t* Wf  = vT + SX;
    ushort_t* Wob = Wf + 3 * SW;
    float* biasf  = (float*)(Wob + SW);
    ushort_t* ao  = xb;   // xb dead after gemm_qkv

    dim3 blk(256);
    {
        long total4 = (long)(SX + 4 * SW + 3 * CDIM) / 4;
        int nb = (int)((total4 + 255) / 256);
        convert_all<<<nb, blk, 0, stream>>>(x, Wq, Wk, Wv, Wo, bq, bk, bv,
                                            xb, Wf, Wob, biasf);
    }
    {
        dim3 g(N_TOK / 128, (3 * CDIM) / 96);   // 32 x 24 = 768 = 3/CU exact
        gemm_qkv<<<g, blk, 0, stream>>>(xb, Wf, biasf, q, k, vT);
    }
    {
        dim3 g((N_TOK / 64) * NH);   // 768 blocks = 3/CU exact
        attn_kernel<<<g, blk, 0, stream>>>(q, k, vT, sim, ao);
    }
    {
        dim3 g(N_TOK / 64, CDIM / 64);
        gemm_out<<<g, blk, 0, stream>>>(ao, Wob, bo, out);
    }
}

// Round 9
// 204.174 us; speedup vs baseline: 1.0008x; 1.0008x over previous
//
#include <hip/hip_runtime.h>
#include <hip/hip_bf16.h>
#include <stdint.h>

#define N_TOK 4096
#define CDIM 768
#define NH 12
#define HD 64
#define SX (N_TOK * CDIM)
#define SW (CDIM * CDIM)

typedef __attribute__((ext_vector_type(8))) short bf16x8;
typedef __attribute__((ext_vector_type(4))) float f32x4;
typedef __attribute__((ext_vector_type(16))) float f32x16;
typedef unsigned short ushort_t;
typedef unsigned int uint_t;

typedef const __attribute__((address_space(1))) void* as1_cvp;
typedef __attribute__((address_space(3))) void* as3_vp;
#define GLD16(g, s) __builtin_amdgcn_global_load_lds((as1_cvp)(g), (as3_vp)(s), 16, 0, 0)

__device__ inline ushort_t f2bf(float f) {
    union { float f; uint_t u; } c; c.f = f;
    uint_t u = (c.u + 0x7FFFu + ((c.u >> 16) & 1u)) >> 16;
    return (ushort_t)u;
}
__device__ inline uint_t pack_bf2(float a, float b) {
    union { __hip_bfloat162 v; uint_t u; } c;
    c.v = __float22bfloat162_rn(make_float2(a, b));
    return c.u;
}

// fp32 -> bf16 one-shot conversion of x, Wq|Wk|Wv (concat), Wo; bq|bk|bv concat fp32.
__global__ __launch_bounds__(256) void convert_all(
    const float* __restrict__ x,
    const float* __restrict__ Wq, const float* __restrict__ Wk,
    const float* __restrict__ Wv, const float* __restrict__ Wo,
    const float* __restrict__ bq, const float* __restrict__ bk, const float* __restrict__ bv,
    ushort_t* __restrict__ xb, ushort_t* __restrict__ Wf,
    ushort_t* __restrict__ Wob, float* __restrict__ biasf)
{
    long i = ((long)blockIdx.x * 256 + threadIdx.x) * 4;
    const float* src; ushort_t* dst; long off;
    if (i < SX)               { src = x;  dst = xb;          off = i; }
    else if (i < SX + SW)     { src = Wq; dst = Wf;          off = i - SX; }
    else if (i < SX + 2*SW)   { src = Wk; dst = Wf + SW;     off = i - SX - SW; }
    else if (i < SX + 3*SW)   { src = Wv; dst = Wf + 2*SW;   off = i - SX - 2*SW; }
    else if (i < SX + 4*SW)   { src = Wo; dst = Wob;         off = i - SX - 3*SW; }
    else if (i < SX + 4*SW + 3*CDIM) {
        long b = i - (SX + 4*SW);
        const float* bs = (b < CDIM) ? bq + b : (b < 2*CDIM) ? bk + (b - CDIM) : bv + (b - 2*CDIM);
        *(float4*)(biasf + b) = *(const float4*)bs;
        return;
    } else return;
    float4 v4 = *(const float4*)(src + off);
    uint2 st = { pack_bf2(v4.x, v4.y), pack_bf2(v4.z, v4.w) };
    *(uint2*)(dst + off) = st;
}

// Fused QKV GEMM v2: 128x96 tiles -> grid 32x24 = 768 blocks = 3/CU EXACT.
// 768/96=8 so each tile lies wholly in Q (y<8), K (y<16) or V. BK=64, GLD16
// staging, XOR-swizzled LDS. out[i][j] = sum_c xb[i][c]*Wf[j][c] + biasf[j];
// q PRE-SCALED by C1; v stored transposed vT[j][i].
__global__ __launch_bounds__(256) void gemm_qkv(
    const ushort_t* __restrict__ xb, const ushort_t* __restrict__ Wf,
    const float* __restrict__ biasf,
    ushort_t* __restrict__ q, ushort_t* __restrict__ k, ushort_t* __restrict__ vT)
{
    __shared__ __align__(16) ushort_t smemAB[224 * 64];   // A[128][64] | B[96][64]
    ushort_t* Asm = smemAB;
    ushort_t* Bsm = smemAB + 128 * 64;
    const int tid = threadIdx.x;
    const int w = tid >> 6, lane = tid & 63;
    const int quad = lane >> 4, l16 = lane & 15;
    const int row0 = blockIdx.x * 128;
    const int col0 = blockIdx.y * 96;
    const int rw = w * 32;
    const int srow = lane >> 3;
    const int sc = ((lane & 7) ^ srow) * 8;
    const int swz = l16 & 7;
    const float C1 = 0.18033688011112042f;   // 0.125 * log2(e)

    f32x4 acc[2][6];
#pragma unroll
    for (int a = 0; a < 2; a++)
#pragma unroll
        for (int b = 0; b < 6; b++) acc[a][b] = (f32x4){0.f, 0.f, 0.f, 0.f};

    for (int kc = 0; kc < CDIM; kc += 64) {
        __syncthreads();
#pragma unroll
        for (int c = 0; c < 4; c++) {
            int ra = w * 32 + c * 8;
            GLD16(xb + (size_t)(row0 + ra + srow) * CDIM + kc + sc, &Asm[ra * 64]);
        }
#pragma unroll
        for (int c = 0; c < 3; c++) {
            int rb_ = w * 24 + c * 8;
            GLD16(Wf + (size_t)(col0 + rb_ + srow) * CDIM + kc + sc, &Bsm[rb_ * 64]);
        }
        __syncthreads();
#pragma unroll
        for (int kk = 0; kk < 2; kk++) {
            const int po = ((kk * 4 + quad) ^ swz) * 8;
            bf16x8 af[2], bfr[6];
#pragma unroll
            for (int rb = 0; rb < 2; rb++)
                af[rb] = *(const bf16x8*)&Asm[(rw + rb * 16 + l16) * 64 + po];
#pragma unroll
            for (int cb = 0; cb < 6; cb++)
                bfr[cb] = *(const bf16x8*)&Bsm[(cb * 16 + l16) * 64 + po];
#pragma unroll
            for (int rb = 0; rb < 2; rb++)
#pragma unroll
                for (int cb = 0; cb < 6; cb++)
                    acc[rb][cb] = __builtin_amdgcn_mfma_f32_16x16x32_bf16(af[rb], bfr[cb], acc[rb][cb], 0, 0, 0);
        }
    }

    if (col0 < 2 * CDIM) {
        const bool isQ = (col0 < CDIM);
        ushort_t* dst = isQ ? q : k;
        const int jb0 = isQ ? col0 : col0 - CDIM;
        const float scale = isQ ? C1 : 1.0f;
#pragma unroll
        for (int cb = 0; cb < 6; cb++) {
            int j = jb0 + cb * 16 + l16;
            float bv_ = biasf[col0 + cb * 16 + l16];
#pragma unroll
            for (int rb = 0; rb < 2; rb++)
#pragma unroll
                for (int r = 0; r < 4; r++) {
                    int i = row0 + rw + rb * 16 + quad * 4 + r;
                    dst[(size_t)i * CDIM + j] = f2bf((acc[rb][cb][r] + bv_) * scale);
                }
        }
    } else {
        // vT: 96j x 128i transpose through smemAB (swizzled), coalesced stores
        const int jv0 = col0 - 2 * CDIM;
        ushort_t* T = smemAB;   // [96][128] = 24 KB <= 28 KB
        __syncthreads();
#pragma unroll
        for (int cb = 0; cb < 6; cb++) {
            int jl = cb * 16 + l16;
            float bv_ = biasf[col0 + jl];
#pragma unroll
            for (int rb = 0; rb < 2; rb++)
#pragma unroll
                for (int r = 0; r < 4; r++) {
                    int i = rw + rb * 16 + quad * 4 + r;
                    T[jl * 128 + (((i >> 3) ^ (jl & 7)) * 8) + (i & 7)] =
                        f2bf(acc[rb][cb][r] + bv_);
                }
        }
        __syncthreads();
#pragma unroll
        for (int p = 0; p < 6; p++) {
            int t = tid + p * 256, jl = t >> 4, i8 = t & 15;
            *(bf16x8*)(vT + (size_t)(jv0 + jl) * N_TOK + row0 + i8 * 8) =
                *(const bf16x8*)&T[jl * 128 + ((i8 ^ (jl & 7)) * 8)];
        }
    }
}

// Output projection: 64x64 tiles (768 blocks = 3/CU balanced). fp32 out.
__global__ __launch_bounds__(256) void gemm_out(
    const ushort_t* __restrict__ A, const ushort_t* __restrict__ W,
    const float* __restrict__ bias, float* __restrict__ out)
{
    __shared__ __align__(16) ushort_t Asm[64 * 64];
    __shared__ __align__(16) ushort_t Bsm[64 * 64];
    const int tid = threadIdx.x;
    const int w = tid >> 6, lane = tid & 63;
    const int quad = lane >> 4, l16 = lane & 15;
    const int row0 = blockIdx.x * 64;
    const int col0 = blockIdx.y * 64;
    const int srow = lane >> 3;
    const int sc = ((lane & 7) ^ srow) * 8;
    const int swz = l16 & 7;

    f32x4 acc[4];
#pragma unroll
    for (int b = 0; b < 4; b++) acc[b] = (f32x4){0.f, 0.f, 0.f, 0.f};

    for (int kc = 0; kc < CDIM; kc += 64) {
        __syncthreads();
#pragma unroll
        for (int c = 0; c < 2; c++) {
            int ra = w * 16 + c * 8;
            GLD16(A + (size_t)(row0 + ra + srow) * CDIM + kc + sc, &Asm[ra * 64]);
            GLD16(W + (size_t)(col0 + ra + srow) * CDIM + kc + sc, &Bsm[ra * 64]);
        }
        __syncthreads();
#pragma unroll
        for (int kk = 0; kk < 2; kk++) {
            const int po = ((kk * 4 + quad) ^ swz) * 8;
            bf16x8 af = *(const bf16x8*)&Asm[(w * 16 + l16) * 64 + po];
#pragma unroll
            for (int cb = 0; cb < 4; cb++) {
                bf16x8 bfr = *(const bf16x8*)&Bsm[(cb * 16 + l16) * 64 + po];
                acc[cb] = __builtin_amdgcn_mfma_f32_16x16x32_bf16(af, bfr, acc[cb], 0, 0, 0);
            }
        }
    }
#pragma unroll
    for (int cb = 0; cb < 4; cb++) {
        int j = col0 + cb * 16 + l16;
        float bv_ = bias[j];
#pragma unroll
        for (int r = 0; r < 4; r++) {
            int i = row0 + w * 16 + quad * 4 + r;
            out[(size_t)i * CDIM + j] = acc[cb][r] + bv_;
        }
    }
}

// Flash attention v11 = v10 (round-7/8 passing 96us kernel) + VALU diet part 2:
//  1. sacc born from the first S-MFMA with a loop-invariant ZERO C-operand
//     (kills 16 v_mov zeroing per tile; MFMA D!=C is legal).
//  2. staging addresses = UNIFORM base pointers (Kt/Vt advanced by s_add on the
//     scalar pipe) + constant per-lane 32-bit offsets -> saddr+voffset form
//     (kills 4x 64-bit per-lane VGPR pointer increments per tile).
// Everything else (queue, swapped QK^T, in-register P, 2-buffer staging, XCD
// swizzle, epilogue) byte-identical to the refcheck'd round-8 kernel.
__global__ __launch_bounds__(256, 3) void attn_kernel(
    const ushort_t* __restrict__ Q, const ushort_t* __restrict__ K,
    const ushort_t* __restrict__ VT, const int* __restrict__ sim,
    ushort_t* __restrict__ Oout)
{
    // smem: K tiles [2][64][64] bf16 | V tiles [2][64][64] bf16 (32 KB total).
    // After the loop, aliased as Of f32[64][66] for the O combine (16.9 KB).
    __shared__ __align__(16) ushort_t smem[16384];
    __shared__ ushort_t bq_[256 * 12];   // per-thread filtered bias queue
    __shared__ float psum[128];          // [qs][jh][l32]

    const int tid = threadIdx.x;
    const int w = tid >> 6, lane = tid & 63;
    const int hi = lane >> 5, l32 = lane & 31;
    const int qs = w >> 1, jh = w & 1;
    const float LOG2E = 1.4426950408889634f;

    // bijective XCD swizzle: 768 = 8 XCDs x 96; each XCD gets 1.5 contiguous heads
    const int lin = blockIdx.x;
    const int g = (lin & 7) * 96 + (lin >> 3);
    const int qbase = (g & 63) * 64;
    const int hoff = (g >> 6) * HD;

    // ---- staging: uniform tile-evolving bases + constant per-lane offsets ----
    const int srow = lane >> 3;
    const int sc = ((lane & 7) ^ srow) * 8;
    const ushort_t* Kt = K;      // uniform; advances 64*CDIM per tile (s_add)
    const ushort_t* Vt = VT;     // uniform; advances 64 per tile (s_add)
    const int klan0 = (w * 16 + srow) * CDIM + hoff + sc;       // per-lane const
    const int klan1 = klan0 + 8 * CDIM;
    const int vlan0 = (hoff + w * 16 + srow) * N_TOK + sc;      // per-lane const
    const int vlan1 = vlan0 + 8 * N_TOK;
    ushort_t* kda = &smem[(w * 16) * 64];
    ushort_t* vda = &smem[8192 + (w * 16) * 64];

#define STAGE(KD, VD) do { \
    GLD16(Kt + klan0, (KD)); GLD16(Kt + klan1, (KD) + 512); \
    GLD16(Vt + vlan0, (VD)); GLD16(Vt + vlan1, (VD) + 512); \
    Kt += 64 * CDIM; Vt += 64; } while (0)

    // ---- per-thread filtered bias queue (thread-private: no barrier needed) ----
    // Lane's sacc element r (hi half) holds S^T[jloc=(r&3)+8*(r>>2)+4*hi][i=l32].
    // Entry j relevant iff bit5(j)==jh && bit2(j)==hi; code = (j>>6)<<4 | r where
    // r = (j&3) + 4*((j&31)>>3).
    ushort_t* myq = &bq_[tid * 12];
    {
        int vb_[10];
        const int* sp = sim + (size_t)(qbase + qs * 32 + l32) * 10;
#pragma unroll
        for (int e = 0; e < 10; e++) vb_[e] = sp[e];
#pragma unroll
        for (int round = 0; round < 10; round++)
#pragma unroll
            for (int i = (round & 1); i + 1 < 10; i += 2) {
                int a = vb_[i], b = vb_[i + 1];
                vb_[i] = min(a, b); vb_[i + 1] = max(a, b);
            }
        int n = 0;
#pragma unroll
        for (int e = 0; e < 10; e++) {
            int j = vb_[e];
            if ((((j >> 5) & 1) == jh) && (((j >> 2) & 1) == hi))
                myq[n++] = (ushort_t)(((j >> 6) << 4) | ((j & 3) + 4 * ((j & 31) >> 3)));
        }
        for (; n < 12; n++) myq[n] = 0xFFFFu;   // sentinel tile 4095
    }
    uint_t c0 = myq[0], c1 = myq[1];
    int qpt = 2;

    // ---- Q fragments (B-operand of S^T MFMA): rows i = qbase+qs*32+l32 ----
    bf16x8 qf[4];
    {
        const ushort_t* qp = Q + (size_t)(qbase + qs * 32 + l32) * CDIM + hoff + hi * 8;
#pragma unroll
        for (int kk = 0; kk < 4; kk++) qf[kk] = *(const bf16x8*)(qp + kk * 16);
    }

    // ---- hoisted tile-invariant LDS read pointers (buf0; buf1 = +4096) ----
    const int swz = l32 & 7;
    const ushort_t* kfp[4];
#pragma unroll
    for (int kk = 0; kk < 4; kk++)
        kfp[kk] = &smem[(jh * 32 + l32) * 64 + (((kk * 2 + hi) ^ swz) * 8)];
    const ushort_t* vfp[2][2];
#pragma unroll
    for (int db = 0; db < 2; db++)
#pragma unroll
        for (int k2 = 0; k2 < 2; k2++)
            vfp[db][k2] = &smem[8192 + db * 2048 + l32 * 64 + (((jh * 4 + k2 * 2 + hi) ^ swz) * 8)];

    STAGE(kda, vda);          // tile 0 -> buf0
    __syncthreads();          // tile0 visible

    float lsum = 0.f;
    const f32x16 Z16 = {0.f,0.f,0.f,0.f,0.f,0.f,0.f,0.f,0.f,0.f,0.f,0.f,0.f,0.f,0.f,0.f};
    f32x16 Oacc0 = Z16;
    f32x16 Oacc1 = Z16;

    // One tile: S^T MFMA (A=K from LDS, B=Q regs; first MFMA takes C=Z16) ->
    // queue-walk bias -> exp2 -> cvt_pk + permlane32_swap -> PV MFMA.
#define TILE_BODY(OFS, J0) do { \
    bf16x8 kf0 = *(const bf16x8*)(kfp[0] + (OFS)); \
    f32x16 sacc = __builtin_amdgcn_mfma_f32_32x32x16_bf16(kf0, qf[0], Z16, 0, 0, 0); \
    _Pragma("unroll") \
    for (int kk = 1; kk < 4; kk++) { \
        bf16x8 kf = *(const bf16x8*)(kfp[kk] + (OFS)); \
        sacc = __builtin_amdgcn_mfma_f32_32x32x16_bf16(kf, qf[kk], sacc, 0, 0, 0); \
    } \
    while ((c0 >> 4) == (uint_t)((J0) >> 6)) { \
        int r = (int)(c0 & 15u); \
        sacc[0]  += (r == 0)  ? LOG2E : 0.f; \
        sacc[1]  += (r == 1)  ? LOG2E : 0.f; \
        sacc[2]  += (r == 2)  ? LOG2E : 0.f; \
        sacc[3]  += (r == 3)  ? LOG2E : 0.f; \
        sacc[4]  += (r == 4)  ? LOG2E : 0.f; \
        sacc[5]  += (r == 5)  ? LOG2E : 0.f; \
        sacc[6]  += (r == 6)  ? LOG2E : 0.f; \
        sacc[7]  += (r == 7)  ? LOG2E : 0.f; \
        sacc[8]  += (r == 8)  ? LOG2E : 0.f; \
        sacc[9]  += (r == 9)  ? LOG2E : 0.f; \
        sacc[10] += (r == 10) ? LOG2E : 0.f; \
        sacc[11] += (r == 11) ? LOG2E : 0.f; \
        sacc[12] += (r == 12) ? LOG2E : 0.f; \
        sacc[13] += (r == 13) ? LOG2E : 0.f; \
        sacc[14] += (r == 14) ? LOG2E : 0.f; \
        sacc[15] += (r == 15) ? LOG2E : 0.f; \
        c0 = c1; c1 = myq[qpt]; qpt++; \
    } \
    float e0  = __builtin_amdgcn_exp2f(sacc[0]); \
    float e1  = __builtin_amdgcn_exp2f(sacc[1]); \
    float e2  = __builtin_amdgcn_exp2f(sacc[2]); \
    float e3  = __builtin_amdgcn_exp2f(sacc[3]); \
    float e4  = __builtin_amdgcn_exp2f(sacc[4]); \
    float e5  = __builtin_amdgcn_exp2f(sacc[5]); \
    float e6  = __builtin_amdgcn_exp2f(sacc[6]); \
    float e7  = __builtin_amdgcn_exp2f(sacc[7]); \
    float e8  = __builtin_amdgcn_exp2f(sacc[8]); \
    float e9  = __builtin_amdgcn_exp2f(sacc[9]); \
    float e10 = __builtin_amdgcn_exp2f(sacc[10]); \
    float e11 = __builtin_amdgcn_exp2f(sacc[11]); \
    float e12 = __builtin_amdgcn_exp2f(sacc[12]); \
    float e13 = __builtin_amdgcn_exp2f(sacc[13]); \
    float e14 = __builtin_amdgcn_exp2f(sacc[14]); \
    float e15 = __builtin_amdgcn_exp2f(sacc[15]); \
    lsum += (((e0+e1)+(e2+e3)) + ((e4+e5)+(e6+e7))) \
          + (((e8+e9)+(e10+e11)) + ((e12+e13)+(e14+e15))); \
    uint_t A0 = pack_bf2(e0, e1),   C0 = pack_bf2(e2, e3); \
    uint_t B0 = pack_bf2(e4, e5),   D0 = pack_bf2(e6, e7); \
    uint_t A1 = pack_bf2(e8, e9),   C1_ = pack_bf2(e10, e11); \
    uint_t B1 = pack_bf2(e12, e13), D1 = pack_bf2(e14, e15); \
    asm("v_permlane32_swap_b32 %0, %1" : "+v"(A0), "+v"(B0)); \
    asm("v_permlane32_swap_b32 %0, %1" : "+v"(C0), "+v"(D0)); \
    asm("v_permlane32_swap_b32 %0, %1" : "+v"(A1), "+v"(B1)); \
    asm("v_permlane32_swap_b32 %0, %1" : "+v"(C1_), "+v"(D1)); \
    union { uint_t u[4]; bf16x8 v; } pa0_, pa1_; \
    pa0_.u[0] = A0; pa0_.u[1] = C0; pa0_.u[2] = B0; pa0_.u[3] = D0; \
    pa1_.u[0] = A1; pa1_.u[1] = C1_; pa1_.u[2] = B1; pa1_.u[3] = D1; \
    { \
        bf16x8 v00 = *(const bf16x8*)(vfp[0][0] + (OFS)); \
        bf16x8 v01 = *(const bf16x8*)(vfp[0][1] + (OFS)); \
        Oacc0 = __builtin_amdgcn_mfma_f32_32x32x16_bf16(pa0_.v, v00, Oacc0, 0, 0, 0); \
        Oacc0 = __builtin_amdgcn_mfma_f32_32x32x16_bf16(pa1_.v, v01, Oacc0, 0, 0, 0); \
        bf16x8 v10 = *(const bf16x8*)(vfp[1][0] + (OFS)); \
        bf16x8 v11 = *(const bf16x8*)(vfp[1][1] + (OFS)); \
        Oacc1 = __builtin_amdgcn_mfma_f32_32x32x16_bf16(pa0_.v, v10, Oacc1, 0, 0, 0); \
        Oacc1 = __builtin_amdgcn_mfma_f32_32x32x16_bf16(pa1_.v, v11, Oacc1, 0, 0, 0); \
    } \
  } while (0)

    // main loop: 64 tiles, 2-deep unrolled for compile-time buffer selection.
    for (int t = 0; t < 64; t += 2) {
        STAGE(kda + 4096, vda + 4096);          // tile t+1 -> buf1
        TILE_BODY(0, t * 64);
        __syncthreads();
        if (t + 2 < 64) STAGE(kda, vda);        // tile t+2 -> buf0
        TILE_BODY(4096, (t + 1) * 64);
        __syncthreads();
    }
#undef TILE_BODY
#undef STAGE

    // ---- epilogue: l reduce, O combine across jh halves, normalize, store ----
    float lt = lsum + __shfl_xor(lsum, 32, 64);
    if (lane < 32) psum[qs * 64 + jh * 32 + l32] = lt;

    float* Of = (float*)smem;   // [64][66]
#define OROWS(OACC, DB, OP) do { \
    _Pragma("unroll") \
    for (int r = 0; r < 16; r++) { \
        int i_ = qs * 32 + (r & 3) + 8 * (r >> 2) + 4 * hi; \
        Of[i_ * 66 + (DB) * 32 + l32] OP (OACC)[r]; \
    } } while (0)

    if (jh == 0) { OROWS(Oacc0, 0, =); OROWS(Oacc1, 1, =); }
    __syncthreads();
    if (jh == 1) { OROWS(Oacc0, 0, +=); OROWS(Oacc1, 1, +=); }
    __syncthreads();
#undef OROWS

    {
        int row = tid >> 2, cs = (tid & 3) * 16;
        int li = row & 31, qr = row >> 5;
        float inv = 1.0f / (psum[qr * 64 + li] + psum[qr * 64 + 32 + li]);
        const float* rp = Of + row * 66 + cs;
        uint_t w0 = pack_bf2(rp[0]  * inv, rp[1]  * inv);
        uint_t w1 = pack_bf2(rp[2]  * inv, rp[3]  * inv);
        uint_t w2 = pack_bf2(rp[4]  * inv, rp[5]  * inv);
        uint_t w3 = pack_bf2(rp[6]  * inv, rp[7]  * inv);
        uint_t w4 = pack_bf2(rp[8]  * inv, rp[9]  * inv);
        uint_t w5 = pack_bf2(rp[10] * inv, rp[11] * inv);
        uint_t w6 = pack_bf2(rp[12] * inv, rp[13] * inv);
        uint_t w7 = pack_bf2(rp[14] * inv, rp[15] * inv);
        union { uint_t u[4]; bf16x8 v; } oA, oB;
        oA.u[0] = w0; oA.u[1] = w1; oA.u[2] = w2; oA.u[3] = w3;
        oB.u[0] = w4; oB.u[1] = w5; oB.u[2] = w6; oB.u[3] = w7;
        ushort_t* op = Oout + (size_t)(qbase + row) * CDIM + hoff + cs;
        *(bf16x8*)op = oA.v;
        *(bf16x8*)(op + 8) = oB.v;
    }
}

extern "C" void kernel_launch(void* const* d_in, const int* in_sizes, int n_in,
                              void* d_out, int out_size, void* d_ws, size_t ws_size,
                              hipStream_t stream)
{
    const float* x   = (const float*)d_in[0];
    const int*   sim = (const int*)d_in[1];
    const float* Wq  = (const float*)d_in[2];
    const float* bq  = (const float*)d_in[3];
    const float* Wk  = (const float*)d_in[4];
    const float* bk  = (const float*)d_in[5];
    const float* Wv  = (const float*)d_in[6];
    const float* bv  = (const float*)d_in[7];
    const float* Wo  = (const float*)d_in[8];
    const float* bo  = (const float*)d_in[9];
    float* out = (float*)d_out;

    // ws layout (ushort units): xb(=ao) | q | k | vT | Wf | Wob | biasf(fp32)
    ushort_t* xb  = (ushort_t*)d_ws;
    ushort_t* q   = xb + SX;
    ushort_t* k   = q + SX;
    ushort_t* vT  = k + SX;
    ushort_t* Wf  = vT + SX;
    ushort_t* Wob = Wf + 3 * SW;
    float* biasf  = (float*)(Wob + SW);
    ushort_t* ao  = xb;   // xb dead after gemm_qkv

    dim3 blk(256);
    {
        long total4 = (long)(SX + 4 * SW + 3 * CDIM) / 4;
        int nb = (int)((total4 + 255) / 256);
        convert_all<<<nb, blk, 0, stream>>>(x, Wq, Wk, Wv, Wo, bq, bk, bv,
                                            xb, Wf, Wob, biasf);
    }
    {
        dim3 g(N_TOK / 128, (3 * CDIM) / 96);   // 32 x 24 = 768 = 3/CU exact
        gemm_qkv<<<g, blk, 0, stream>>>(xb, Wf, biasf, q, k, vT);
    }
    {
        dim3 g((N_TOK / 64) * NH);   // 768 blocks = 3/CU exact
        attn_kernel<<<g, blk, 0, stream>>>(q, k, vT, sim, ao);
    }
    {
        dim3 g(N_TOK / 64, CDIM / 64);
        gemm_out<<<g, blk, 0, stream>>>(ao, Wob, bo, out);
    }
}

// Round 10
// 197.768 us; speedup vs baseline: 1.0332x; 1.0324x over previous
//
#include <hip/hip_runtime.h>
#include <hip/hip_bf16.h>
#include <stdint.h>

#define N_TOK 4096
#define CDIM 768
#define NH 12
#define HD 64
#define SX (N_TOK * CDIM)
#define SW (CDIM * CDIM)

typedef __attribute__((ext_vector_type(8))) short bf16x8;
typedef __attribute__((ext_vector_type(4))) float f32x4;
typedef __attribute__((ext_vector_type(16))) float f32x16;
typedef unsigned short ushort_t;
typedef unsigned int uint_t;

typedef const __attribute__((address_space(1))) void* as1_cvp;
typedef __attribute__((address_space(3))) void* as3_vp;
#define GLD16(g, s) __builtin_amdgcn_global_load_lds((as1_cvp)(g), (as3_vp)(s), 16, 0, 0)

__device__ inline ushort_t f2bf(float f) {
    union { float f; uint_t u; } c; c.f = f;
    uint_t u = (c.u + 0x7FFFu + ((c.u >> 16) & 1u)) >> 16;
    return (ushort_t)u;
}
__device__ inline uint_t pack_bf2(float a, float b) {
    union { __hip_bfloat162 v; uint_t u; } c;
    c.v = __float22bfloat162_rn(make_float2(a, b));
    return c.u;
}

// fp32 -> bf16 one-shot conversion of x, Wq|Wk|Wv (concat), Wo; bq|bk|bv concat fp32.
__global__ __launch_bounds__(256) void convert_all(
    const float* __restrict__ x,
    const float* __restrict__ Wq, const float* __restrict__ Wk,
    const float* __restrict__ Wv, const float* __restrict__ Wo,
    const float* __restrict__ bq, const float* __restrict__ bk, const float* __restrict__ bv,
    ushort_t* __restrict__ xb, ushort_t* __restrict__ Wf,
    ushort_t* __restrict__ Wob, float* __restrict__ biasf)
{
    long i = ((long)blockIdx.x * 256 + threadIdx.x) * 4;
    const float* src; ushort_t* dst; long off;
    if (i < SX)               { src = x;  dst = xb;          off = i; }
    else if (i < SX + SW)     { src = Wq; dst = Wf;          off = i - SX; }
    else if (i < SX + 2*SW)   { src = Wk; dst = Wf + SW;     off = i - SX - SW; }
    else if (i < SX + 3*SW)   { src = Wv; dst = Wf + 2*SW;   off = i - SX - 2*SW; }
    else if (i < SX + 4*SW)   { src = Wo; dst = Wob;         off = i - SX - 3*SW; }
    else if (i < SX + 4*SW + 3*CDIM) {
        long b = i - (SX + 4*SW);
        const float* bs = (b < CDIM) ? bq + b : (b < 2*CDIM) ? bk + (b - CDIM) : bv + (b - 2*CDIM);
        *(float4*)(biasf + b) = *(const float4*)bs;
        return;
    } else return;
    float4 v4 = *(const float4*)(src + off);
    uint2 st = { pack_bf2(v4.x, v4.y), pack_bf2(v4.z, v4.w) };
    *(uint2*)(dst + off) = st;
}

// Fused QKV GEMM v3: 128x96 tiles (768 blocks), BK=64, now DOUBLE-BUFFERED with
// the attn-proven skeleton: STAGE(next buf) -> COMPUTE(cur buf) -> barrier.
// The GLD16 latency hides under the MFMA phase instead of being drained by the
// pre-compute barrier (old 2-phase structure exposed it every K-iter).
// Indexing/swizzle/epilogue byte-identical to the round-8/9 passing kernel.
__global__ __launch_bounds__(256) void gemm_qkv(
    const ushort_t* __restrict__ xb, const ushort_t* __restrict__ Wf,
    const float* __restrict__ biasf,
    ushort_t* __restrict__ q, ushort_t* __restrict__ k, ushort_t* __restrict__ vT)
{
    // [2 bufs][A 128x64 | B 96x64] = 57,344 B (< 64 KB static limit)
    __shared__ __align__(16) ushort_t smemAB[2 * 224 * 64];
    const int tid = threadIdx.x;
    const int w = tid >> 6, lane = tid & 63;
    const int quad = lane >> 4, l16 = lane & 15;
    const int row0 = blockIdx.x * 128;
    const int col0 = blockIdx.y * 96;
    const int rw = w * 32;
    const int srow = lane >> 3;
    const int sc = ((lane & 7) ^ srow) * 8;
    const int swz = l16 & 7;
    const float C1 = 0.18033688011112042f;   // 0.125 * log2(e)

    f32x4 acc[2][6];
#pragma unroll
    for (int a = 0; a < 2; a++)
#pragma unroll
        for (int b = 0; b < 6; b++) acc[a][b] = (f32x4){0.f, 0.f, 0.f, 0.f};

    // BUF is an element offset (0 or 14336); A at +0, B at +8192 within a buf.
#define STAGEQ(BUF, KC) do { \
    _Pragma("unroll") \
    for (int c = 0; c < 4; c++) { \
        int ra = w * 32 + c * 8; \
        GLD16(xb + (size_t)(row0 + ra + srow) * CDIM + (KC) + sc, &smemAB[(BUF) + ra * 64]); \
    } \
    _Pragma("unroll") \
    for (int c = 0; c < 3; c++) { \
        int rb_ = w * 24 + c * 8; \
        GLD16(Wf + (size_t)(col0 + rb_ + srow) * CDIM + (KC) + sc, &smemAB[(BUF) + 8192 + rb_ * 64]); \
    } } while (0)

#define COMPQ(BUF) do { \
    _Pragma("unroll") \
    for (int kk = 0; kk < 2; kk++) { \
        const int po = ((kk * 4 + quad) ^ swz) * 8; \
        bf16x8 af[2], bfr[6]; \
        _Pragma("unroll") \
        for (int rb = 0; rb < 2; rb++) \
            af[rb] = *(const bf16x8*)&smemAB[(BUF) + (rw + rb * 16 + l16) * 64 + po]; \
        _Pragma("unroll") \
        for (int cb = 0; cb < 6; cb++) \
            bfr[cb] = *(const bf16x8*)&smemAB[(BUF) + 8192 + (cb * 16 + l16) * 64 + po]; \
        _Pragma("unroll") \
        for (int rb = 0; rb < 2; rb++) \
            _Pragma("unroll") \
            for (int cb = 0; cb < 6; cb++) \
                acc[rb][cb] = __builtin_amdgcn_mfma_f32_16x16x32_bf16(af[rb], bfr[cb], acc[rb][cb], 0, 0, 0); \
    } } while (0)

    STAGEQ(0, 0);
    __syncthreads();                     // buf0 (kc=0) visible
    for (int kc = 0; kc < CDIM; kc += 128) {
        STAGEQ(14336, kc + 64);          // next K-slab -> buf1 (kc+64 <= 704 always)
        COMPQ(0);
        __syncthreads();                 // buf1 visible; buf0 reads done (WAR)
        if (kc + 128 < CDIM) STAGEQ(0, kc + 128);
        COMPQ(14336);
        __syncthreads();
    }
#undef COMPQ
#undef STAGEQ

    if (col0 < 2 * CDIM) {
        const bool isQ = (col0 < CDIM);
        ushort_t* dst = isQ ? q : k;
        const int jb0 = isQ ? col0 : col0 - CDIM;
        const float scale = isQ ? C1 : 1.0f;
#pragma unroll
        for (int cb = 0; cb < 6; cb++) {
            int j = jb0 + cb * 16 + l16;
            float bv_ = biasf[col0 + cb * 16 + l16];
#pragma unroll
            for (int rb = 0; rb < 2; rb++)
#pragma unroll
                for (int r = 0; r < 4; r++) {
                    int i = row0 + rw + rb * 16 + quad * 4 + r;
                    dst[(size_t)i * CDIM + j] = f2bf((acc[rb][cb][r] + bv_) * scale);
                }
        }
    } else {
        // vT: 96j x 128i transpose through smemAB buf0 (swizzled), coalesced stores
        const int jv0 = col0 - 2 * CDIM;
        ushort_t* T = smemAB;   // [96][128] = 24 KB
        __syncthreads();
#pragma unroll
        for (int cb = 0; cb < 6; cb++) {
            int jl = cb * 16 + l16;
            float bv_ = biasf[col0 + jl];
#pragma unroll
            for (int rb = 0; rb < 2; rb++)
#pragma unroll
                for (int r = 0; r < 4; r++) {
                    int i = rw + rb * 16 + quad * 4 + r;
                    T[jl * 128 + (((i >> 3) ^ (jl & 7)) * 8) + (i & 7)] =
                        f2bf(acc[rb][cb][r] + bv_);
                }
        }
        __syncthreads();
#pragma unroll
        for (int p = 0; p < 6; p++) {
            int t = tid + p * 256, jl = t >> 4, i8 = t & 15;
            *(bf16x8*)(vT + (size_t)(jv0 + jl) * N_TOK + row0 + i8 * 8) =
                *(const bf16x8*)&T[jl * 128 + ((i8 ^ (jl & 7)) * 8)];
        }
    }
}

// Output projection v2: 64x64 tiles (768 blocks = 3/CU), DOUBLE-BUFFERED K-loop
// (same skeleton as gemm_qkv v3 / attn). LDS 32 KB. fp32 out.
__global__ __launch_bounds__(256) void gemm_out(
    const ushort_t* __restrict__ A, const ushort_t* __restrict__ W,
    const float* __restrict__ bias, float* __restrict__ out)
{
    // [2 bufs][A 64x64 | B 64x64] = 32,768 B
    __shared__ __align__(16) ushort_t smemAB[2 * 128 * 64];
    const int tid = threadIdx.x;
    const int w = tid >> 6, lane = tid & 63;
    const int quad = lane >> 4, l16 = lane & 15;
    const int row0 = blockIdx.x * 64;
    const int col0 = blockIdx.y * 64;
    const int srow = lane >> 3;
    const int sc = ((lane & 7) ^ srow) * 8;
    const int swz = l16 & 7;

    f32x4 acc[4];
#pragma unroll
    for (int b = 0; b < 4; b++) acc[b] = (f32x4){0.f, 0.f, 0.f, 0.f};

#define STAGEO(BUF, KC) do { \
    _Pragma("unroll") \
    for (int c = 0; c < 2; c++) { \
        int ra = w * 16 + c * 8; \
        GLD16(A + (size_t)(row0 + ra + srow) * CDIM + (KC) + sc, &smemAB[(BUF) + ra * 64]); \
        GLD16(W + (size_t)(col0 + ra + srow) * CDIM + (KC) + sc, &smemAB[(BUF) + 4096 + ra * 64]); \
    } } while (0)

#define COMPO(BUF) do { \
    _Pragma("unroll") \
    for (int kk = 0; kk < 2; kk++) { \
        const int po = ((kk * 4 + quad) ^ swz) * 8; \
        bf16x8 af = *(const bf16x8*)&smemAB[(BUF) + (w * 16 + l16) * 64 + po]; \
        _Pragma("unroll") \
        for (int cb = 0; cb < 4; cb++) { \
            bf16x8 bfr = *(const bf16x8*)&smemAB[(BUF) + 4096 + (cb * 16 + l16) * 64 + po]; \
            acc[cb] = __builtin_amdgcn_mfma_f32_16x16x32_bf16(af, bfr, acc[cb], 0, 0, 0); \
        } \
    } } while (0)

    STAGEO(0, 0);
    __syncthreads();
    for (int kc = 0; kc < CDIM; kc += 128) {
        STAGEO(8192, kc + 64);
        COMPO(0);
        __syncthreads();
        if (kc + 128 < CDIM) STAGEO(0, kc + 128);
        COMPO(8192);
        __syncthreads();
    }
#undef COMPO
#undef STAGEO

#pragma unroll
    for (int cb = 0; cb < 4; cb++) {
        int j = col0 + cb * 16 + l16;
        float bv_ = bias[j];
#pragma unroll
        for (int r = 0; r < 4; r++) {
            int i = row0 + w * 16 + quad * 4 + r;
            out[(size_t)i * CDIM + j] = acc[cb][r] + bv_;
        }
    }
}

// Flash attention v11 (round-9 PASSING kernel, 95.4us, byte-identical): swapped
// QK^T 32x32x16 MFMA, in-register P via cvt_pk + permlane32_swap, per-thread
// filtered bias queue, 2-buffer GLD16 staging, XCD swizzle, Z16-born sacc,
// uniform staging bases.
__global__ __launch_bounds__(256, 3) void attn_kernel(
    const ushort_t* __restrict__ Q, const ushort_t* __restrict__ K,
    const ushort_t* __restrict__ VT, const int* __restrict__ sim,
    ushort_t* __restrict__ Oout)
{
    // smem: K tiles [2][64][64] bf16 | V tiles [2][64][64] bf16 (32 KB total).
    // After the loop, aliased as Of f32[64][66] for the O combine (16.9 KB).
    __shared__ __align__(16) ushort_t smem[16384];
    __shared__ ushort_t bq_[256 * 12];   // per-thread filtered bias queue
    __shared__ float psum[128];          // [qs][jh][l32]

    const int tid = threadIdx.x;
    const int w = tid >> 6, lane = tid & 63;
    const int hi = lane >> 5, l32 = lane & 31;
    const int qs = w >> 1, jh = w & 1;
    const float LOG2E = 1.4426950408889634f;

    // bijective XCD swizzle: 768 = 8 XCDs x 96; each XCD gets 1.5 contiguous heads
    const int lin = blockIdx.x;
    const int g = (lin & 7) * 96 + (lin >> 3);
    const int qbase = (g & 63) * 64;
    const int hoff = (g >> 6) * HD;

    // ---- staging: uniform tile-evolving bases + constant per-lane offsets ----
    const int srow = lane >> 3;
    const int sc = ((lane & 7) ^ srow) * 8;
    const ushort_t* Kt = K;      // uniform; advances 64*CDIM per tile (s_add)
    const ushort_t* Vt = VT;     // uniform; advances 64 per tile (s_add)
    const int klan0 = (w * 16 + srow) * CDIM + hoff + sc;       // per-lane const
    const int klan1 = klan0 + 8 * CDIM;
    const int vlan0 = (hoff + w * 16 + srow) * N_TOK + sc;      // per-lane const
    const int vlan1 = vlan0 + 8 * N_TOK;
    ushort_t* kda = &smem[(w * 16) * 64];
    ushort_t* vda = &smem[8192 + (w * 16) * 64];

#define STAGE(KD, VD) do { \
    GLD16(Kt + klan0, (KD)); GLD16(Kt + klan1, (KD) + 512); \
    GLD16(Vt + vlan0, (VD)); GLD16(Vt + vlan1, (VD) + 512); \
    Kt += 64 * CDIM; Vt += 64; } while (0)

    // ---- per-thread filtered bias queue (thread-private: no barrier needed) ----
    // Lane's sacc element r (hi half) holds S^T[jloc=(r&3)+8*(r>>2)+4*hi][i=l32].
    // Entry j relevant iff bit5(j)==jh && bit2(j)==hi; code = (j>>6)<<4 | r where
    // r = (j&3) + 4*((j&31)>>3).
    ushort_t* myq = &bq_[tid * 12];
    {
        int vb_[10];
        const int* sp = sim + (size_t)(qbase + qs * 32 + l32) * 10;
#pragma unroll
        for (int e = 0; e < 10; e++) vb_[e] = sp[e];
#pragma unroll
        for (int round = 0; round < 10; round++)
#pragma unroll
            for (int i = (round & 1); i + 1 < 10; i += 2) {
                int a = vb_[i], b = vb_[i + 1];
                vb_[i] = min(a, b); vb_[i + 1] = max(a, b);
            }
        int n = 0;
#pragma unroll
        for (int e = 0; e < 10; e++) {
            int j = vb_[e];
            if ((((j >> 5) & 1) == jh) && (((j >> 2) & 1) == hi))
                myq[n++] = (ushort_t)(((j >> 6) << 4) | ((j & 3) + 4 * ((j & 31) >> 3)));
        }
        for (; n < 12; n++) myq[n] = 0xFFFFu;   // sentinel tile 4095
    }
    uint_t c0 = myq[0], c1 = myq[1];
    int qpt = 2;

    // ---- Q fragments (B-operand of S^T MFMA): rows i = qbase+qs*32+l32 ----
    bf16x8 qf[4];
    {
        const ushort_t* qp = Q + (size_t)(qbase + qs * 32 + l32) * CDIM + hoff + hi * 8;
#pragma unroll
        for (int kk = 0; kk < 4; kk++) qf[kk] = *(const bf16x8*)(qp + kk * 16);
    }

    // ---- hoisted tile-invariant LDS read pointers (buf0; buf1 = +4096) ----
    const int swz = l32 & 7;
    const ushort_t* kfp[4];
#pragma unroll
    for (int kk = 0; kk < 4; kk++)
        kfp[kk] = &smem[(jh * 32 + l32) * 64 + (((kk * 2 + hi) ^ swz) * 8)];
    const ushort_t* vfp[2][2];
#pragma unroll
    for (int db = 0; db < 2; db++)
#pragma unroll
        for (int k2 = 0; k2 < 2; k2++)
            vfp[db][k2] = &smem[8192 + db * 2048 + l32 * 64 + (((jh * 4 + k2 * 2 + hi) ^ swz) * 8)];

    STAGE(kda, vda);          // tile 0 -> buf0
    __syncthreads();          // tile0 visible

    float lsum = 0.f;
    const f32x16 Z16 = {0.f,0.f,0.f,0.f,0.f,0.f,0.f,0.f,0.f,0.f,0.f,0.f,0.f,0.f,0.f,0.f};
    f32x16 Oacc0 = Z16;
    f32x16 Oacc1 = Z16;

    // One tile: S^T MFMA (A=K from LDS, B=Q regs; first MFMA takes C=Z16) ->
    // queue-walk bias -> exp2 -> cvt_pk + permlane32_swap -> PV MFMA.
#define TILE_BODY(OFS, J0) do { \
    bf16x8 kf0 = *(const bf16x8*)(kfp[0] + (OFS)); \
    f32x16 sacc = __builtin_amdgcn_mfma_f32_32x32x16_bf16(kf0, qf[0], Z16, 0, 0, 0); \
    _Pragma("unroll") \
    for (int kk = 1; kk < 4; kk++) { \
        bf16x8 kf = *(const bf16x8*)(kfp[kk] + (OFS)); \
        sacc = __builtin_amdgcn_mfma_f32_32x32x16_bf16(kf, qf[kk], sacc, 0, 0, 0); \
    } \
    while ((c0 >> 4) == (uint_t)((J0) >> 6)) { \
        int r = (int)(c0 & 15u); \
        sacc[0]  += (r == 0)  ? LOG2E : 0.f; \
        sacc[1]  += (r == 1)  ? LOG2E : 0.f; \
        sacc[2]  += (r == 2)  ? LOG2E : 0.f; \
        sacc[3]  += (r == 3)  ? LOG2E : 0.f; \
        sacc[4]  += (r == 4)  ? LOG2E : 0.f; \
        sacc[5]  += (r == 5)  ? LOG2E : 0.f; \
        sacc[6]  += (r == 6)  ? LOG2E : 0.f; \
        sacc[7]  += (r == 7)  ? LOG2E : 0.f; \
        sacc[8]  += (r == 8)  ? LOG2E : 0.f; \
        sacc[9]  += (r == 9)  ? LOG2E : 0.f; \
        sacc[10] += (r == 10) ? LOG2E : 0.f; \
        sacc[11] += (r == 11) ? LOG2E : 0.f; \
        sacc[12] += (r == 12) ? LOG2E : 0.f; \
        sacc[13] += (r == 13) ? LOG2E : 0.f; \
        sacc[14] += (r == 14) ? LOG2E : 0.f; \
        sacc[15] += (r == 15) ? LOG2E : 0.f; \
        c0 = c1; c1 = myq[qpt]; qpt++; \
    } \
    float e0  = __builtin_amdgcn_exp2f(sacc[0]); \
    float e1  = __builtin_amdgcn_exp2f(sacc[1]); \
    float e2  = __builtin_amdgcn_exp2f(sacc[2]); \
    float e3  = __builtin_amdgcn_exp2f(sacc[3]); \
    float e4  = __builtin_amdgcn_exp2f(sacc[4]); \
    float e5  = __builtin_amdgcn_exp2f(sacc[5]); \
    float e6  = __builtin_amdgcn_exp2f(sacc[6]); \
    float e7  = __builtin_amdgcn_exp2f(sacc[7]); \
    float e8  = __builtin_amdgcn_exp2f(sacc[8]); \
    float e9  = __builtin_amdgcn_exp2f(sacc[9]); \
    float e10 = __builtin_amdgcn_exp2f(sacc[10]); \
    float e11 = __builtin_amdgcn_exp2f(sacc[11]); \
    float e12 = __builtin_amdgcn_exp2f(sacc[12]); \
    float e13 = __builtin_amdgcn_exp2f(sacc[13]); \
    float e14 = __builtin_amdgcn_exp2f(sacc[14]); \
    float e15 = __builtin_amdgcn_exp2f(sacc[15]); \
    lsum += (((e0+e1)+(e2+e3)) + ((e4+e5)+(e6+e7))) \
          + (((e8+e9)+(e10+e11)) + ((e12+e13)+(e14+e15))); \
    uint_t A0 = pack_bf2(e0, e1),   C0 = pack_bf2(e2, e3); \
    uint_t B0 = pack_bf2(e4, e5),   D0 = pack_bf2(e6, e7); \
    uint_t A1 = pack_bf2(e8, e9),   C1_ = pack_bf2(e10, e11); \
    uint_t B1 = pack_bf2(e12, e13), D1 = pack_bf2(e14, e15); \
    asm("v_permlane32_swap_b32 %0, %1" : "+v"(A0), "+v"(B0)); \
    asm("v_permlane32_swap_b32 %0, %1" : "+v"(C0), "+v"(D0)); \
    asm("v_permlane32_swap_b32 %0, %1" : "+v"(A1), "+v"(B1)); \
    asm("v_permlane32_swap_b32 %0, %1" : "+v"(C1_), "+v"(D1)); \
    union { uint_t u[4]; bf16x8 v; } pa0_, pa1_; \
    pa0_.u[0] = A0; pa0_.u[1] = C0; pa0_.u[2] = B0; pa0_.u[3] = D0; \
    pa1_.u[0] = A1; pa1_.u[1] = C1_; pa1_.u[2] = B1; pa1_.u[3] = D1; \
    { \
        bf16x8 v00 = *(const bf16x8*)(vfp[0][0] + (OFS)); \
        bf16x8 v01 = *(const bf16x8*)(vfp[0][1] + (OFS)); \
        Oacc0 = __builtin_amdgcn_mfma_f32_32x32x16_bf16(pa0_.v, v00, Oacc0, 0, 0, 0); \
        Oacc0 = __builtin_amdgcn_mfma_f32_32x32x16_bf16(pa1_.v, v01, Oacc0, 0, 0, 0); \
        bf16x8 v10 = *(const bf16x8*)(vfp[1][0] + (OFS)); \
        bf16x8 v11 = *(const bf16x8*)(vfp[1][1] + (OFS)); \
        Oacc1 = __builtin_amdgcn_mfma_f32_32x32x16_bf16(pa0_.v, v10, Oacc1, 0, 0, 0); \
        Oacc1 = __builtin_amdgcn_mfma_f32_32x32x16_bf16(pa1_.v, v11, Oacc1, 0, 0, 0); \
    } \
  } while (0)

    // main loop: 64 tiles, 2-deep unrolled for compile-time buffer selection.
    for (int t = 0; t < 64; t += 2) {
        STAGE(kda + 4096, vda + 4096);          // tile t+1 -> buf1
        TILE_BODY(0, t * 64);
        __syncthreads();
        if (t + 2 < 64) STAGE(kda, vda);        // tile t+2 -> buf0
        TILE_BODY(4096, (t + 1) * 64);
        __syncthreads();
    }
#undef TILE_BODY
#undef STAGE

    // ---- epilogue: l reduce, O combine across jh halves, normalize, store ----
    float lt = lsum + __shfl_xor(lsum, 32, 64);
    if (lane < 32) psum[qs * 64 + jh * 32 + l32] = lt;

    float* Of = (float*)smem;   // [64][66]
#define OROWS(OACC, DB, OP) do { \
    _Pragma("unroll") \
    for (int r = 0; r < 16; r++) { \
        int i_ = qs * 32 + (r & 3) + 8 * (r >> 2) + 4 * hi; \
        Of[i_ * 66 + (DB) * 32 + l32] OP (OACC)[r]; \
    } } while (0)

    if (jh == 0) { OROWS(Oacc0, 0, =); OROWS(Oacc1, 1, =); }
    __syncthreads();
    if (jh == 1) { OROWS(Oacc0, 0, +=); OROWS(Oacc1, 1, +=); }
    __syncthreads();
#undef OROWS

    {
        int row = tid >> 2, cs = (tid & 3) * 16;
        int li = row & 31, qr = row >> 5;
        float inv = 1.0f / (psum[qr * 64 + li] + psum[qr * 64 + 32 + li]);
        const float* rp = Of + row * 66 + cs;
        uint_t w0 = pack_bf2(rp[0]  * inv, rp[1]  * inv);
        uint_t w1 = pack_bf2(rp[2]  * inv, rp[3]  * inv);
        uint_t w2 = pack_bf2(rp[4]  * inv, rp[5]  * inv);
        uint_t w3 = pack_bf2(rp[6]  * inv, rp[7]  * inv);
        uint_t w4 = pack_bf2(rp[8]  * inv, rp[9]  * inv);
        uint_t w5 = pack_bf2(rp[10] * inv, rp[11] * inv);
        uint_t w6 = pack_bf2(rp[12] * inv, rp[13] * inv);
        uint_t w7 = pack_bf2(rp[14] * inv, rp[15] * inv);
        union { uint_t u[4]; bf16x8 v; } oA, oB;
        oA.u[0] = w0; oA.u[1] = w1; oA.u[2] = w2; oA.u[3] = w3;
        oB.u[0] = w4; oB.u[1] = w5; oB.u[2] = w6; oB.u[3] = w7;
        ushort_t* op = Oout + (size_t)(qbase + row) * CDIM + hoff + cs;
        *(bf16x8*)op = oA.v;
        *(bf16x8*)(op + 8) = oB.v;
    }
}

extern "C" void kernel_launch(void* const* d_in, const int* in_sizes, int n_in,
                              void* d_out, int out_size, void* d_ws, size_t ws_size,
                              hipStream_t stream)
{
    const float* x   = (const float*)d_in[0];
    const int*   sim = (const int*)d_in[1];
    const float* Wq  = (const float*)d_in[2];
    const float* bq  = (const float*)d_in[3];
    const float* Wk  = (const float*)d_in[4];
    const float* bk  = (const float*)d_in[5];
    const float* Wv  = (const float*)d_in[6];
    const float* bv  = (const float*)d_in[7];
    const float* Wo  = (const float*)d_in[8];
    const float* bo  = (const float*)d_in[9];
    float* out = (float*)d_out;

    // ws layout (ushort units): xb(=ao) | q | k | vT | Wf | Wob | biasf(fp32)
    ushort_t* xb  = (ushort_t*)d_ws;
    ushort_t* q   = xb + SX;
    ushort_t* k   = q + SX;
    ushort_t* vT  = k + SX;
    ushort_t* Wf  = vT + SX;
    ushort_t* Wob = Wf + 3 * SW;
    float* biasf  = (float*)(Wob + SW);
    ushort_t* ao  = xb;   // xb dead after gemm_qkv

    dim3 blk(256);
    {
        long total4 = (long)(SX + 4 * SW + 3 * CDIM) / 4;
        int nb = (int)((total4 + 255) / 256);
        convert_all<<<nb, blk, 0, stream>>>(x, Wq, Wk, Wv, Wo, bq, bk, bv,
                                            xb, Wf, Wob, biasf);
    }
    {
        dim3 g(N_TOK / 128, (3 * CDIM) / 96);   // 32 x 24 = 768 = 3/CU exact
        gemm_qkv<<<g, blk, 0, stream>>>(xb, Wf, biasf, q, k, vT);
    }
    {
        dim3 g((N_TOK / 64) * NH);   // 768 blocks = 3/CU exact
        attn_kernel<<<g, blk, 0, stream>>>(q, k, vT, sim, ao);
    }
    {
        dim3 g(N_TOK / 64, CDIM / 64);
        gemm_out<<<g, blk, 0, stream>>>(ao, Wob, bo, out);
    }
}

// Round 11
// 194.848 us; speedup vs baseline: 1.0487x; 1.0150x over previous
//
#include <hip/hip_runtime.h>
#include <hip/hip_bf16.h>
#include <stdint.h>

#define N_TOK 4096
#define CDIM 768
#define NH 12
#define HD 64
#define SX (N_TOK * CDIM)
#define SW (CDIM * CDIM)

typedef __attribute__((ext_vector_type(8))) short bf16x8;
typedef __attribute__((ext_vector_type(4))) float f32x4;
typedef __attribute__((ext_vector_type(16))) float f32x16;
typedef unsigned short ushort_t;
typedef unsigned int uint_t;

typedef const __attribute__((address_space(1))) void* as1_cvp;
typedef __attribute__((address_space(3))) void* as3_vp;
#define GLD16(g, s) __builtin_amdgcn_global_load_lds((as1_cvp)(g), (as3_vp)(s), 16, 0, 0)

__device__ inline ushort_t f2bf(float f) {
    union { float f; uint_t u; } c; c.f = f;
    uint_t u = (c.u + 0x7FFFu + ((c.u >> 16) & 1u)) >> 16;
    return (ushort_t)u;
}
__device__ inline uint_t pack_bf2(float a, float b) {
    union { __hip_bfloat162 v; uint_t u; } c;
    c.v = __float22bfloat162_rn(make_float2(a, b));
    return c.u;
}

// fp32 -> bf16 one-shot conversion of x, Wq|Wk|Wv (concat), Wo; bq|bk|bv concat fp32.
__global__ __launch_bounds__(256) void convert_all(
    const float* __restrict__ x,
    const float* __restrict__ Wq, const float* __restrict__ Wk,
    const float* __restrict__ Wv, const float* __restrict__ Wo,
    const float* __restrict__ bq, const float* __restrict__ bk, const float* __restrict__ bv,
    ushort_t* __restrict__ xb, ushort_t* __restrict__ Wf,
    ushort_t* __restrict__ Wob, float* __restrict__ biasf)
{
    long i = ((long)blockIdx.x * 256 + threadIdx.x) * 4;
    const float* src; ushort_t* dst; long off;
    if (i < SX)               { src = x;  dst = xb;          off = i; }
    else if (i < SX + SW)     { src = Wq; dst = Wf;          off = i - SX; }
    else if (i < SX + 2*SW)   { src = Wk; dst = Wf + SW;     off = i - SX - SW; }
    else if (i < SX + 3*SW)   { src = Wv; dst = Wf + 2*SW;   off = i - SX - 2*SW; }
    else if (i < SX + 4*SW)   { src = Wo; dst = Wob;         off = i - SX - 3*SW; }
    else if (i < SX + 4*SW + 3*CDIM) {
        long b = i - (SX + 4*SW);
        const float* bs = (b < CDIM) ? bq + b : (b < 2*CDIM) ? bk + (b - CDIM) : bv + (b - 2*CDIM);
        *(float4*)(biasf + b) = *(const float4*)bs;
        return;
    } else return;
    float4 v4 = *(const float4*)(src + off);
    uint2 st = { pack_bf2(v4.x, v4.y), pack_bf2(v4.z, v4.w) };
    *(uint2*)(dst + off) = st;
}

// Fused QKV GEMM v4: 128x96 tiles (768 blocks = 3/CU). Round-10's full dbuf
// (57.3KB) capped occupancy at 2 blocks/CU (57.3*3 > 160KB). v4 restores 3/CU
// (45KB total): A keeps a GLD16 DOUBLE-buffer (2x16KB); B is a SINGLE 12KB LDS
// buffer fed by T14 reg-staging -- B(k+1) global loads issued BEFORE COMPUTE(k)
// (latency hidden under MFMAs), ds_write after the WAR barrier, cheap publish
// barrier (lgkm only). LDS write layout identical to GLD16's, read side unchanged.
__global__ __launch_bounds__(256) void gemm_qkv(
    const ushort_t* __restrict__ xb, const ushort_t* __restrict__ Wf,
    const float* __restrict__ biasf,
    ushort_t* __restrict__ q, ushort_t* __restrict__ k, ushort_t* __restrict__ vT)
{
    __shared__ __align__(16) ushort_t As[2 * 128 * 64];   // 32 KB (A dbuf)
    __shared__ __align__(16) ushort_t Bs[96 * 64];        // 12 KB (B single)
    const int tid = threadIdx.x;
    const int w = tid >> 6, lane = tid & 63;
    const int quad = lane >> 4, l16 = lane & 15;
    const int row0 = blockIdx.x * 128;
    const int col0 = blockIdx.y * 96;
    const int rw = w * 32;
    const int srow = lane >> 3;
    const int sc = ((lane & 7) ^ srow) * 8;
    const int swz = l16 & 7;
    const float C1 = 0.18033688011112042f;   // 0.125 * log2(e)

    f32x4 acc[2][6];
#pragma unroll
    for (int a = 0; a < 2; a++)
#pragma unroll
        for (int b = 0; b < 6; b++) acc[a][b] = (f32x4){0.f, 0.f, 0.f, 0.f};

    uint4 breg0, breg1, breg2;   // B reg-staging (T14): 3 x 16B per lane

#define STAGEA(BUF, KC) do { \
    _Pragma("unroll") \
    for (int c = 0; c < 4; c++) { \
        int ra = w * 32 + c * 8; \
        GLD16(xb + (size_t)(row0 + ra + srow) * CDIM + (KC) + sc, &As[(BUF) + ra * 64]); \
    } } while (0)

#define BLOAD(KC) do { \
    breg0 = *(const uint4*)(Wf + (size_t)(col0 + w * 24 + 0 + srow) * CDIM + (KC) + sc); \
    breg1 = *(const uint4*)(Wf + (size_t)(col0 + w * 24 + 8 + srow) * CDIM + (KC) + sc); \
    breg2 = *(const uint4*)(Wf + (size_t)(col0 + w * 24 + 16 + srow) * CDIM + (KC) + sc); \
    } while (0)

#define BWRITE() do { \
    *(uint4*)&Bs[(w * 24 + 0 + srow) * 64 + (lane & 7) * 8] = breg0; \
    *(uint4*)&Bs[(w * 24 + 8 + srow) * 64 + (lane & 7) * 8] = breg1; \
    *(uint4*)&Bs[(w * 24 + 16 + srow) * 64 + (lane & 7) * 8] = breg2; \
    } while (0)

#define COMPQ(BUF) do { \
    _Pragma("unroll") \
    for (int kk = 0; kk < 2; kk++) { \
        const int po = ((kk * 4 + quad) ^ swz) * 8; \
        bf16x8 af[2], bfr[6]; \
        _Pragma("unroll") \
        for (int rb = 0; rb < 2; rb++) \
            af[rb] = *(const bf16x8*)&As[(BUF) + (rw + rb * 16 + l16) * 64 + po]; \
        _Pragma("unroll") \
        for (int cb = 0; cb < 6; cb++) \
            bfr[cb] = *(const bf16x8*)&Bs[(cb * 16 + l16) * 64 + po]; \
        _Pragma("unroll") \
        for (int rb = 0; rb < 2; rb++) \
            _Pragma("unroll") \
            for (int cb = 0; cb < 6; cb++) \
                acc[rb][cb] = __builtin_amdgcn_mfma_f32_16x16x32_bf16(af[rb], bfr[cb], acc[rb][cb], 0, 0, 0); \
    } } while (0)

    // prologue: A(0) -> buf0 (async), B(0) -> regs -> LDS, publish
    STAGEA(0, 0);
    BLOAD(0);
    BWRITE();                    // compiler inserts vmcnt wait for breg
    __syncthreads();             // A(0) drained + B(0) visible

    // 12 K-steps, unrolled x2 for static A-buffer selection. Per step:
    // issue {A(k+1) gld16, B(k+1) reg loads} -> COMPUTE(k) -> barrier (WAR on Bs;
    // drains the hidden loads) -> BWRITE(k+1) -> barrier (publish, lgkm only).
    for (int kc = 0; kc < CDIM; kc += 128) {
        const bool more = (kc + 128 < CDIM);
        // step kc (A in buf0)
        STAGEA(8192, kc + 64);           // kc+64 <= 704 always valid
        BLOAD(kc + 64);
        COMPQ(0);
        __syncthreads();
        BWRITE();
        __syncthreads();
        // step kc+64 (A in buf1)
        if (more) { STAGEA(0, kc + 128); BLOAD(kc + 128); }
        COMPQ(8192);
        __syncthreads();
        if (more) BWRITE();
        __syncthreads();
    }
#undef COMPQ
#undef BWRITE
#undef BLOAD
#undef STAGEA

    if (col0 < 2 * CDIM) {
        const bool isQ = (col0 < CDIM);
        ushort_t* dst = isQ ? q : k;
        const int jb0 = isQ ? col0 : col0 - CDIM;
        const float scale = isQ ? C1 : 1.0f;
#pragma unroll
        for (int cb = 0; cb < 6; cb++) {
            int j = jb0 + cb * 16 + l16;
            float bv_ = biasf[col0 + cb * 16 + l16];
#pragma unroll
            for (int rb = 0; rb < 2; rb++)
#pragma unroll
                for (int r = 0; r < 4; r++) {
                    int i = row0 + rw + rb * 16 + quad * 4 + r;
                    dst[(size_t)i * CDIM + j] = f2bf((acc[rb][cb][r] + bv_) * scale);
                }
        }
    } else {
        // vT: 96j x 128i transpose through As (dead after loop), coalesced stores
        const int jv0 = col0 - 2 * CDIM;
        ushort_t* T = As;   // [96][128] = 24 KB <= 32 KB
        __syncthreads();
#pragma unroll
        for (int cb = 0; cb < 6; cb++) {
            int jl = cb * 16 + l16;
            float bv_ = biasf[col0 + jl];
#pragma unroll
            for (int rb = 0; rb < 2; rb++)
#pragma unroll
                for (int r = 0; r < 4; r++) {
                    int i = rw + rb * 16 + quad * 4 + r;
                    T[jl * 128 + (((i >> 3) ^ (jl & 7)) * 8) + (i & 7)] =
                        f2bf(acc[rb][cb][r] + bv_);
                }
        }
        __syncthreads();
#pragma unroll
        for (int p = 0; p < 6; p++) {
            int t = tid + p * 256, jl = t >> 4, i8 = t & 15;
            *(bf16x8*)(vT + (size_t)(jv0 + jl) * N_TOK + row0 + i8 * 8) =
                *(const bf16x8*)&T[jl * 128 + ((i8 ^ (jl & 7)) * 8)];
        }
    }
}

// Output projection v2 (round-10 passing version, byte-identical): 64x64 tiles
// (768 blocks = 3/CU), DOUBLE-BUFFERED K-loop. LDS 32 KB (5/CU capacity). fp32 out.
__global__ __launch_bounds__(256) void gemm_out(
    const ushort_t* __restrict__ A, const ushort_t* __restrict__ W,
    const float* __restrict__ bias, float* __restrict__ out)
{
    // [2 bufs][A 64x64 | B 64x64] = 32,768 B
    __shared__ __align__(16) ushort_t smemAB[2 * 128 * 64];
    const int tid = threadIdx.x;
    const int w = tid >> 6, lane = tid & 63;
    const int quad = lane >> 4, l16 = lane & 15;
    const int row0 = blockIdx.x * 64;
    const int col0 = blockIdx.y * 64;
    const int srow = lane >> 3;
    const int sc = ((lane & 7) ^ srow) * 8;
    const int swz = l16 & 7;

    f32x4 acc[4];
#pragma unroll
    for (int b = 0; b < 4; b++) acc[b] = (f32x4){0.f, 0.f, 0.f, 0.f};

#define STAGEO(BUF, KC) do { \
    _Pragma("unroll") \
    for (int c = 0; c < 2; c++) { \
        int ra = w * 16 + c * 8; \
        GLD16(A + (size_t)(row0 + ra + srow) * CDIM + (KC) + sc, &smemAB[(BUF) + ra * 64]); \
        GLD16(W + (size_t)(col0 + ra + srow) * CDIM + (KC) + sc, &smemAB[(BUF) + 4096 + ra * 64]); \
    } } while (0)

#define COMPO(BUF) do { \
    _Pragma("unroll") \
    for (int kk = 0; kk < 2; kk++) { \
        const int po = ((kk * 4 + quad) ^ swz) * 8; \
        bf16x8 af = *(const bf16x8*)&smemAB[(BUF) + (w * 16 + l16) * 64 + po]; \
        _Pragma("unroll") \
        for (int cb = 0; cb < 4; cb++) { \
            bf16x8 bfr = *(const bf16x8*)&smemAB[(BUF) + 4096 + (cb * 16 + l16) * 64 + po]; \
            acc[cb] = __builtin_amdgcn_mfma_f32_16x16x32_bf16(af, bfr, acc[cb], 0, 0, 0); \
        } \
    } } while (0)

    STAGEO(0, 0);
    __syncthreads();
    for (int kc = 0; kc < CDIM; kc += 128) {
        STAGEO(8192, kc + 64);
        COMPO(0);
        __syncthreads();
        if (kc + 128 < CDIM) STAGEO(0, kc + 128);
        COMPO(8192);
        __syncthreads();
    }
#undef COMPO
#undef STAGEO

#pragma unroll
    for (int cb = 0; cb < 4; cb++) {
        int j = col0 + cb * 16 + l16;
        float bv_ = bias[j];
#pragma unroll
        for (int r = 0; r < 4; r++) {
            int i = row0 + w * 16 + quad * 4 + r;
            out[(size_t)i * CDIM + j] = acc[cb][r] + bv_;
        }
    }
}

// Flash attention v11 (round-9/10 PASSING kernel, ~96us, byte-identical): swapped
// QK^T 32x32x16 MFMA, in-register P via cvt_pk + permlane32_swap, per-thread
// filtered bias queue, 2-buffer GLD16 staging, XCD swizzle, Z16-born sacc,
// uniform staging bases.
__global__ __launch_bounds__(256, 3) void attn_kernel(
    const ushort_t* __restrict__ Q, const ushort_t* __restrict__ K,
    const ushort_t* __restrict__ VT, const int* __restrict__ sim,
    ushort_t* __restrict__ Oout)
{
    // smem: K tiles [2][64][64] bf16 | V tiles [2][64][64] bf16 (32 KB total).
    // After the loop, aliased as Of f32[64][66] for the O combine (16.9 KB).
    __shared__ __align__(16) ushort_t smem[16384];
    __shared__ ushort_t bq_[256 * 12];   // per-thread filtered bias queue
    __shared__ float psum[128];          // [qs][jh][l32]

    const int tid = threadIdx.x;
    const int w = tid >> 6, lane = tid & 63;
    const int hi = lane >> 5, l32 = lane & 31;
    const int qs = w >> 1, jh = w & 1;
    const float LOG2E = 1.4426950408889634f;

    // bijective XCD swizzle: 768 = 8 XCDs x 96; each XCD gets 1.5 contiguous heads
    const int lin = blockIdx.x;
    const int g = (lin & 7) * 96 + (lin >> 3);
    const int qbase = (g & 63) * 64;
    const int hoff = (g >> 6) * HD;

    // ---- staging: uniform tile-evolving bases + constant per-lane offsets ----
    const int srow = lane >> 3;
    const int sc = ((lane & 7) ^ srow) * 8;
    const ushort_t* Kt = K;      // uniform; advances 64*CDIM per tile (s_add)
    const ushort_t* Vt = VT;     // uniform; advances 64 per tile (s_add)
    const int klan0 = (w * 16 + srow) * CDIM + hoff + sc;       // per-lane const
    const int klan1 = klan0 + 8 * CDIM;
    const int vlan0 = (hoff + w * 16 + srow) * N_TOK + sc;      // per-lane const
    const int vlan1 = vlan0 + 8 * N_TOK;
    ushort_t* kda = &smem[(w * 16) * 64];
    ushort_t* vda = &smem[8192 + (w * 16) * 64];

#define STAGE(KD, VD) do { \
    GLD16(Kt + klan0, (KD)); GLD16(Kt + klan1, (KD) + 512); \
    GLD16(Vt + vlan0, (VD)); GLD16(Vt + vlan1, (VD) + 512); \
    Kt += 64 * CDIM; Vt += 64; } while (0)

    // ---- per-thread filtered bias queue (thread-private: no barrier needed) ----
    // Lane's sacc element r (hi half) holds S^T[jloc=(r&3)+8*(r>>2)+4*hi][i=l32].
    // Entry j relevant iff bit5(j)==jh && bit2(j)==hi; code = (j>>6)<<4 | r where
    // r = (j&3) + 4*((j&31)>>3).
    ushort_t* myq = &bq_[tid * 12];
    {
        int vb_[10];
        const int* sp = sim + (size_t)(qbase + qs * 32 + l32) * 10;
#pragma unroll
        for (int e = 0; e < 10; e++) vb_[e] = sp[e];
#pragma unroll
        for (int round = 0; round < 10; round++)
#pragma unroll
            for (int i = (round & 1); i + 1 < 10; i += 2) {
                int a = vb_[i], b = vb_[i + 1];
                vb_[i] = min(a, b); vb_[i + 1] = max(a, b);
            }
        int n = 0;
#pragma unroll
        for (int e = 0; e < 10; e++) {
            int j = vb_[e];
            if ((((j >> 5) & 1) == jh) && (((j >> 2) & 1) == hi))
                myq[n++] = (ushort_t)(((j >> 6) << 4) | ((j & 3) + 4 * ((j & 31) >> 3)));
        }
        for (; n < 12; n++) myq[n] = 0xFFFFu;   // sentinel tile 4095
    }
    uint_t c0 = myq[0], c1 = myq[1];
    int qpt = 2;

    // ---- Q fragments (B-operand of S^T MFMA): rows i = qbase+qs*32+l32 ----
    bf16x8 qf[4];
    {
        const ushort_t* qp = Q + (size_t)(qbase + qs * 32 + l32) * CDIM + hoff + hi * 8;
#pragma unroll
        for (int kk = 0; kk < 4; kk++) qf[kk] = *(const bf16x8*)(qp + kk * 16);
    }

    // ---- hoisted tile-invariant LDS read pointers (buf0; buf1 = +4096) ----
    const int swz = l32 & 7;
    const ushort_t* kfp[4];
#pragma unroll
    for (int kk = 0; kk < 4; kk++)
        kfp[kk] = &smem[(jh * 32 + l32) * 64 + (((kk * 2 + hi) ^ swz) * 8)];
    const ushort_t* vfp[2][2];
#pragma unroll
    for (int db = 0; db < 2; db++)
#pragma unroll
        for (int k2 = 0; k2 < 2; k2++)
            vfp[db][k2] = &smem[8192 + db * 2048 + l32 * 64 + (((jh * 4 + k2 * 2 + hi) ^ swz) * 8)];

    STAGE(kda, vda);          // tile 0 -> buf0
    __syncthreads();          // tile0 visible

    float lsum = 0.f;
    const f32x16 Z16 = {0.f,0.f,0.f,0.f,0.f,0.f,0.f,0.f,0.f,0.f,0.f,0.f,0.f,0.f,0.f,0.f};
    f32x16 Oacc0 = Z16;
    f32x16 Oacc1 = Z16;

    // One tile: S^T MFMA (A=K from LDS, B=Q regs; first MFMA takes C=Z16) ->
    // queue-walk bias -> exp2 -> cvt_pk + permlane32_swap -> PV MFMA.
#define TILE_BODY(OFS, J0) do { \
    bf16x8 kf0 = *(const bf16x8*)(kfp[0] + (OFS)); \
    f32x16 sacc = __builtin_amdgcn_mfma_f32_32x32x16_bf16(kf0, qf[0], Z16, 0, 0, 0); \
    _Pragma("unroll") \
    for (int kk = 1; kk < 4; kk++) { \
        bf16x8 kf = *(const bf16x8*)(kfp[kk] + (OFS)); \
        sacc = __builtin_amdgcn_mfma_f32_32x32x16_bf16(kf, qf[kk], sacc, 0, 0, 0); \
    } \
    while ((c0 >> 4) == (uint_t)((J0) >> 6)) { \
        int r = (int)(c0 & 15u); \
        sacc[0]  += (r == 0)  ? LOG2E : 0.f; \
        sacc[1]  += (r == 1)  ? LOG2E : 0.f; \
        sacc[2]  += (r == 2)  ? LOG2E : 0.f; \
        sacc[3]  += (r == 3)  ? LOG2E : 0.f; \
        sacc[4]  += (r == 4)  ? LOG2E : 0.f; \
        sacc[5]  += (r == 5)  ? LOG2E : 0.f; \
        sacc[6]  += (r == 6)  ? LOG2E : 0.f; \
        sacc[7]  += (r == 7)  ? LOG2E : 0.f; \
        sacc[8]  += (r == 8)  ? LOG2E : 0.f; \
        sacc[9]  += (r == 9)  ? LOG2E : 0.f; \
        sacc[10] += (r == 10) ? LOG2E : 0.f; \
        sacc[11] += (r == 11) ? LOG2E : 0.f; \
        sacc[12] += (r == 12) ? LOG2E : 0.f; \
        sacc[13] += (r == 13) ? LOG2E : 0.f; \
        sacc[14] += (r == 14) ? LOG2E : 0.f; \
        sacc[15] += (r == 15) ? LOG2E : 0.f; \
        c0 = c1; c1 = myq[qpt]; qpt++; \
    } \
    float e0  = __builtin_amdgcn_exp2f(sacc[0]); \
    float e1  = __builtin_amdgcn_exp2f(sacc[1]); \
    float e2  = __builtin_amdgcn_exp2f(sacc[2]); \
    float e3  = __builtin_amdgcn_exp2f(sacc[3]); \
    float e4  = __builtin_amdgcn_exp2f(sacc[4]); \
    float e5  = __builtin_amdgcn_exp2f(sacc[5]); \
    float e6  = __builtin_amdgcn_exp2f(sacc[6]); \
    float e7  = __builtin_amdgcn_exp2f(sacc[7]); \
    float e8  = __builtin_amdgcn_exp2f(sacc[8]); \
    float e9  = __builtin_amdgcn_exp2f(sacc[9]); \
    float e10 = __builtin_amdgcn_exp2f(sacc[10]); \
    float e11 = __builtin_amdgcn_exp2f(sacc[11]); \
    float e12 = __builtin_amdgcn_exp2f(sacc[12]); \
    float e13 = __builtin_amdgcn_exp2f(sacc[13]); \
    float e14 = __builtin_amdgcn_exp2f(sacc[14]); \
    float e15 = __builtin_amdgcn_exp2f(sacc[15]); \
    lsum += (((e0+e1)+(e2+e3)) + ((e4+e5)+(e6+e7))) \
          + (((e8+e9)+(e10+e11)) + ((e12+e13)+(e14+e15))); \
    uint_t A0 = pack_bf2(e0, e1),   C0 = pack_bf2(e2, e3); \
    uint_t B0 = pack_bf2(e4, e5),   D0 = pack_bf2(e6, e7); \
    uint_t A1 = pack_bf2(e8, e9),   C1_ = pack_bf2(e10, e11); \
    uint_t B1 = pack_bf2(e12, e13), D1 = pack_bf2(e14, e15); \
    asm("v_permlane32_swap_b32 %0, %1" : "+v"(A0), "+v"(B0)); \
    asm("v_permlane32_swap_b32 %0, %1" : "+v"(C0), "+v"(D0)); \
    asm("v_permlane32_swap_b32 %0, %1" : "+v"(A1), "+v"(B1)); \
    asm("v_permlane32_swap_b32 %0, %1" : "+v"(C1_), "+v"(D1)); \
    union { uint_t u[4]; bf16x8 v; } pa0_, pa1_; \
    pa0_.u[0] = A0; pa0_.u[1] = C0; pa0_.u[2] = B0; pa0_.u[3] = D0; \
    pa1_.u[0] = A1; pa1_.u[1] = C1_; pa1_.u[2] = B1; pa1_.u[3] = D1; \
    { \
        bf16x8 v00 = *(const bf16x8*)(vfp[0][0] + (OFS)); \
        bf16x8 v01 = *(const bf16x8*)(vfp[0][1] + (OFS)); \
        Oacc0 = __builtin_amdgcn_mfma_f32_32x32x16_bf16(pa0_.v, v00, Oacc0, 0, 0, 0); \
        Oacc0 = __builtin_amdgcn_mfma_f32_32x32x16_bf16(pa1_.v, v01, Oacc0, 0, 0, 0); \
        bf16x8 v10 = *(const bf16x8*)(vfp[1][0] + (OFS)); \
        bf16x8 v11 = *(const bf16x8*)(vfp[1][1] + (OFS)); \
        Oacc1 = __builtin_amdgcn_mfma_f32_32x32x16_bf16(pa0_.v, v10, Oacc1, 0, 0, 0); \
        Oacc1 = __builtin_amdgcn_mfma_f32_32x32x16_bf16(pa1_.v, v11, Oacc1, 0, 0, 0); \
    } \
  } while (0)

    // main loop: 64 tiles, 2-deep unrolled for compile-time buffer selection.
    for (int t = 0; t < 64; t += 2) {
        STAGE(kda + 4096, vda + 4096);          // tile t+1 -> buf1
        TILE_BODY(0, t * 64);
        __syncthreads();
        if (t + 2 < 64) STAGE(kda, vda);        // tile t+2 -> buf0
        TILE_BODY(4096, (t + 1) * 64);
        __syncthreads();
    }
#undef TILE_BODY
#undef STAGE

    // ---- epilogue: l reduce, O combine across jh halves, normalize, store ----
    float lt = lsum + __shfl_xor(lsum, 32, 64);
    if (lane < 32) psum[qs * 64 + jh * 32 + l32] = lt;

    float* Of = (float*)smem;   // [64][66]
#define OROWS(OACC, DB, OP) do { \
    _Pragma("unroll") \
    for (int r = 0; r < 16; r++) { \
        int i_ = qs * 32 + (r & 3) + 8 * (r >> 2) + 4 * hi; \
        Of[i_ * 66 + (DB) * 32 + l32] OP (OACC)[r]; \
    } } while (0)

    if (jh == 0) { OROWS(Oacc0, 0, =); OROWS(Oacc1, 1, =); }
    __syncthreads();
    if (jh == 1) { OROWS(Oacc0, 0, +=); OROWS(Oacc1, 1, +=); }
    __syncthreads();
#undef OROWS

    {
        int row = tid >> 2, cs = (tid & 3) * 16;
        int li = row & 31, qr = row >> 5;
        float inv = 1.0f / (psum[qr * 64 + li] + psum[qr * 64 + 32 + li]);
        const float* rp = Of + row * 66 + cs;
        uint_t w0 = pack_bf2(rp[0]  * inv, rp[1]  * inv);
        uint_t w1 = pack_bf2(rp[2]  * inv, rp[3]  * inv);
        uint_t w2 = pack_bf2(rp[4]  * inv, rp[5]  * inv);
        uint_t w3 = pack_bf2(rp[6]  * inv, rp[7]  * inv);
        uint_t w4 = pack_bf2(rp[8]  * inv, rp[9]  * inv);
        uint_t w5 = pack_bf2(rp[10] * inv, rp[11] * inv);
        uint_t w6 = pack_bf2(rp[12] * inv, rp[13] * inv);
        uint_t w7 = pack_bf2(rp[14] * inv, rp[15] * inv);
        union { uint_t u[4]; bf16x8 v; } oA, oB;
        oA.u[0] = w0; oA.u[1] = w1; oA.u[2] = w2; oA.u[3] = w3;
        oB.u[0] = w4; oB.u[1] = w5; oB.u[2] = w6; oB.u[3] = w7;
        ushort_t* op = Oout + (size_t)(qbase + row) * CDIM + hoff + cs;
        *(bf16x8*)op = oA.v;
        *(bf16x8*)(op + 8) = oB.v;
    }
}

extern "C" void kernel_launch(void* const* d_in, const int* in_sizes, int n_in,
                              void* d_out, int out_size, void* d_ws, size_t ws_size,
                              hipStream_t stream)
{
    const float* x   = (const float*)d_in[0];
    const int*   sim = (const int*)d_in[1];
    const float* Wq  = (const float*)d_in[2];
    const float* bq  = (const float*)d_in[3];
    const float* Wk  = (const float*)d_in[4];
    const float* bk  = (const float*)d_in[5];
    const float* Wv  = (const float*)d_in[6];
    const float* bv  = (const float*)d_in[7];
    const float* Wo  = (const float*)d_in[8];
    const float* bo  = (const float*)d_in[9];
    float* out = (float*)d_out;

    // ws layout (ushort units): xb(=ao) | q | k | vT | Wf | Wob | biasf(fp32)
    ushort_t* xb  = (ushort_t*)d_ws;
    ushort_t* q   = xb + SX;
    ushort_t* k   = q + SX;
    ushort_t* vT  = k + SX;
    ushort_t* Wf  = vT + SX;
    ushort_t* Wob = Wf + 3 * SW;
    float* biasf  = (float*)(Wob + SW);
    ushort_t* ao  = xb;   // xb dead after gemm_qkv

    dim3 blk(256);
    {
        long total4 = (long)(SX + 4 * SW + 3 * CDIM) / 4;
        int nb = (int)((total4 + 255) / 256);
        convert_all<<<nb, blk, 0, stream>>>(x, Wq, Wk, Wv, Wo, bq, bk, bv,
                                            xb, Wf, Wob, biasf);
    }
    {
        dim3 g(N_TOK / 128, (3 * CDIM) / 96);   // 32 x 24 = 768 = 3/CU exact
        gemm_qkv<<<g, blk, 0, stream>>>(xb, Wf, biasf, q, k, vT);
    }
    {
        dim3 g((N_TOK / 64) * NH);   // 768 blocks = 3/CU exact
        attn_kernel<<<g, blk, 0, stream>>>(q, k, vT, sim, ao);
    }
    {
        dim3 g(N_TOK / 64, CDIM / 64);
        gemm_out<<<g, blk, 0, stream>>>(ao, Wob, bo, out);
    }
}